// Round 9
// baseline (506.668 us; speedup 1.0000x reference)
//
#include <hip/hip_runtime.h>

typedef __attribute__((ext_vector_type(4))) float f32x4;
typedef __attribute__((ext_vector_type(8))) short short8;
typedef __attribute__((ext_vector_type(8))) unsigned short ushort8;
typedef unsigned short u16;
typedef unsigned int u32;

#define DMODEL 1024
#define DINNER 2048
#define NH     32
#define DIP    4288
#define DIP_PAD 4352
#define CONVD  2176
#define LSEQ   2048
#define ROWS   8192
#define NCHUNK 32

static __device__ __forceinline__ float bf2f(u16 u) {
  u32 x = ((u32)u) << 16;
  return __builtin_bit_cast(float, x);
}
static __device__ __forceinline__ u16 f2bf(float f) {
  u32 x = __builtin_bit_cast(u32, f);
  x += 0x7fffu + ((x >> 16) & 1u);
  return (u16)(x >> 16);
}
static __device__ __forceinline__ f32x4 mfma16(short8 a, short8 b, f32x4 c) {
  return __builtin_amdgcn_mfma_f32_16x16x32_bf16(a, b, c, 0, 0, 0);
}

#define GLDS(gp, lp)                                                     \
  __builtin_amdgcn_global_load_lds(                                     \
      (const __attribute__((address_space(1))) void*)(gp),              \
      (__attribute__((address_space(3))) void*)(lp), 16, 0, 0)

// ---------------- f32 -> bf16 weight cast ----------------
__global__ __launch_bounds__(256) void k_cast(const float* __restrict__ s, u16* __restrict__ d) {
  size_t i = ((size_t)blockIdx.x * 256 + threadIdx.x) * 4;
  float4 v = *(const float4*)(s + i);
  u32 lo = (u32)f2bf(v.x) | ((u32)f2bf(v.y) << 16);
  u32 hi = (u32)f2bf(v.z) | ((u32)f2bf(v.w) << 16);
  *(uint2*)(d + i) = make_uint2(lo, hi);
}

// ---------------- res = h + r ; hnorm = rmsnorm(res)*w (bf16) ----------------
__global__ __launch_bounds__(256) void k_addnorm(const float* __restrict__ h,
                                                 const float* __restrict__ r,
                                                 const float* __restrict__ nw,
                                                 float* __restrict__ res,
                                                 u16* __restrict__ hn) {
  int row = blockIdx.x, t = threadIdx.x;
  const float4* hp = (const float4*)(h + (size_t)row * DMODEL);
  const float4* rp = (const float4*)(r + (size_t)row * DMODEL);
  float4 a = hp[t], b = rp[t];
  float4 s;
  s.x = a.x + b.x; s.y = a.y + b.y; s.z = a.z + b.z; s.w = a.w + b.w;
  ((float4*)(res + (size_t)row * DMODEL))[t] = s;
  float ss = s.x * s.x + s.y * s.y + s.z * s.z + s.w * s.w;
  for (int m = 32; m; m >>= 1) ss += __shfl_xor(ss, m);
  __shared__ float wsum[4];
  if ((t & 63) == 0) wsum[t >> 6] = ss;
  __syncthreads();
  float tot = wsum[0] + wsum[1] + wsum[2] + wsum[3];
  float rinv = rsqrtf(tot * (1.0f / DMODEL) + 1e-5f);
  float4 w4 = ((const float4*)nw)[t];
  u32 lo = (u32)f2bf(s.x * rinv * w4.x) | ((u32)f2bf(s.y * rinv * w4.y) << 16);
  u32 hi = (u32)f2bf(s.z * rinv * w4.z) | ((u32)f2bf(s.w * rinv * w4.w) << 16);
  *(uint2*)(hn + (size_t)row * DMODEL + t * 4) = make_uint2(lo, hi);
}

// ---------------- bf16 MFMA GEMM: 128x256 tile, 8 waves, BK=64 ----------------
// Depth-2 counted-vmcnt pipeline, triple-buffered LDS (3 x 48 KB), dual barrier:
//   STAGE(t+2) -> vmcnt(12) [in-order retirement => buf[t] drained; t+1/t+2 stay
//   in flight] -> barrier -> ds_read buf[t] (both k-halves) -> lgkmcnt(0) ->
//   barrier (read-complete rendezvous; makes next iter's overwrite of buf[t]
//   safe) -> setprio(1) 32 MFMA setprio(0).
// XCD supertile remap: xcd = bid%8 owns an 8-brow band; within it 8x4 supertiles
// (A 2MB + B 2MB fits the 4MB XCD L2).
template <int MODE>
__global__ __launch_bounds__(512) void k_gemm(const u16* __restrict__ A,
                                              const u16* __restrict__ Bw, int K, int nN,
                                              float* __restrict__ outf,
                                              u16* __restrict__ zb, u16* __restrict__ xb,
                                              float* __restrict__ dtp,
                                              const float* __restrict__ dt_bias) {
  constexpr int ABY = 128 * 64 * 2;   // 16 KB A tile
  constexpr int BBY = 256 * 64 * 2;   // 32 KB B tile
  constexpr int TB = ABY + BBY;       // 48 KB per buffer
  __shared__ char lds[3 * TB];        // 144 KB

  const int tid = threadIdx.x, wave = tid >> 6, lane = tid & 63;
  const int wm = wave >> 2, wn = wave & 3;
  const int lr = lane & 15, lg = lane >> 4;

  // XCD supertile remap: gridDim.x % 8 == 0; brows-per-XCD = (gridDim.x/8)/nN = 8.
  const int xcd = blockIdx.x & 7;
  const int l = blockIdx.x >> 3;
  const int nstFull = nN >> 2;
  int brl, bc;
  if (l < (nstFull << 5)) {
    int st = l >> 5, off = l & 31;
    brl = off & 7;
    bc = (st << 2) + (off >> 3);
  } else {
    int rem = l - (nstFull << 5);
    brl = rem & 7;
    bc = (nstFull << 2) + (rem >> 3);
  }
  const int brow = (xcd * 8 + brl) * 128;
  const int bcol = bc * 256;
  const int NK = K >> 6;

  size_t srcA[2], srcB[4];
#pragma unroll
  for (int g = 0; g < 2; ++g) {
    int d = g * 8192 + tid * 16;
    int s = d ^ (((d >> 7) & 7) << 4);
    srcA[g] = (size_t)(brow + (s >> 7)) * K + ((s & 127) >> 1);
  }
#pragma unroll
  for (int g = 0; g < 4; ++g) {
    int d = g * 8192 + tid * 16;
    int s = d ^ (((d >> 7) & 7) << 4);
    srcB[g] = (size_t)(bcol + (s >> 7)) * K + ((s & 127) >> 1);
  }

  auto STAGE = [&](int buf, int kt) {
    char* base = lds + buf * TB;
    size_t koff = (size_t)kt * 64;
#pragma unroll
    for (int g = 0; g < 2; ++g)
      GLDS(A + srcA[g] + koff, base + g * 8192 + wave * 1024);
#pragma unroll
    for (int g = 0; g < 4; ++g)
      GLDS(Bw + srcB[g] + koff, base + ABY + g * 8192 + wave * 1024);
  };

  int offA[4][2], offB[4][2];
#pragma unroll
  for (int i = 0; i < 4; ++i)
#pragma unroll
    for (int ks = 0; ks < 2; ++ks) {
      int rA = wm * 64 + i * 16 + lr;
      offA[i][ks] = (rA * 128 + ks * 64 + lg * 16) ^ ((lr & 7) << 4);
      int rB = wn * 64 + i * 16 + lr;
      offB[i][ks] = ABY + ((rB * 128 + ks * 64 + lg * 16) ^ ((lr & 7) << 4));
    }

  f32x4 acc[4][4] = {};
  STAGE(0, 0);
  STAGE(1, 1);
  int cur = 0;
  for (int t = 0; t < NK; ++t) {
    if (t + 2 < NK) {
      int nb = cur + 2;
      if (nb >= 3) nb -= 3;
      STAGE(nb, t + 2);
      asm volatile("s_waitcnt vmcnt(12)" ::: "memory");
    } else if (t + 1 < NK) {
      asm volatile("s_waitcnt vmcnt(6)" ::: "memory");
    } else {
      asm volatile("s_waitcnt vmcnt(0)" ::: "memory");
    }
    __builtin_amdgcn_sched_barrier(0);
    __builtin_amdgcn_s_barrier();
    __builtin_amdgcn_sched_barrier(0);
    const char* bb = lds + cur * TB;
    short8 af[4][2], bfr[4][2];
#pragma unroll
    for (int i = 0; i < 4; ++i)
#pragma unroll
      for (int ks = 0; ks < 2; ++ks) {
        af[i][ks] = *(const short8*)(bb + offA[i][ks]);
        bfr[i][ks] = *(const short8*)(bb + offB[i][ks]);
      }
    asm volatile("s_waitcnt lgkmcnt(0)" ::: "memory");
    __builtin_amdgcn_sched_barrier(0);
    __builtin_amdgcn_s_barrier();
    __builtin_amdgcn_sched_barrier(0);
    __builtin_amdgcn_s_setprio(1);
#pragma unroll
    for (int ks = 0; ks < 2; ++ks)
#pragma unroll
      for (int i = 0; i < 4; ++i)
#pragma unroll
        for (int j = 0; j < 4; ++j) acc[i][j] = mfma16(af[i][ks], bfr[j][ks], acc[i][j]);
    __builtin_amdgcn_s_setprio(0);
    __builtin_amdgcn_sched_barrier(0);
    cur = cur + 1;
    if (cur >= 3) cur = 0;
  }

  const int mb = brow + wm * 64 + lg * 4;
  const int nb = bcol + wn * 64 + lr;
#pragma unroll
  for (int i = 0; i < 4; ++i)
#pragma unroll
    for (int j = 0; j < 4; ++j)
#pragma unroll
      for (int rr = 0; rr < 4; ++rr) {
        int m = mb + i * 16 + rr;
        int n = nb + j * 16;
        float v = acc[i][j][rr];
        if constexpr (MODE == 1) {
          outf[(size_t)m * 1024 + n] = v;
        } else {
          if (n < DINNER) {
            zb[(size_t)m * DINNER + n] = f2bf(v);
          } else if (n < DINNER + CONVD) {
            xb[(size_t)m * CONVD + (n - DINNER)] = f2bf(v);
          } else if (n < DIP) {
            int h2 = n - (DINNER + CONVD);  // 0..63
            float uu = v + dt_bias[h2 & 31];
            float sp = (uu > 20.f) ? uu : log1pf(expf(uu));
            int bb2 = m >> 11, tt = m & 2047;
            int obb = bb2, ot = tt;
            if (h2 >= 32) { obb = bb2 + 4; ot = 2047 - tt; }
            dtp[((size_t)(obb << 11) + ot) * NH + (h2 & 31)] = sp;
          }
        }
      }
}

// ---------------- depthwise causal conv (k=4) + SiLU, 8 chans/thread ----------------
__global__ __launch_bounds__(256) void k_conv(const u16* __restrict__ xbc,
                                              const float* __restrict__ cw,
                                              const float* __restrict__ cb,
                                              u16* __restrict__ xc, u16* __restrict__ bm,
                                              u16* __restrict__ cm) {
  int e = blockIdx.x * 256 + threadIdx.x;  // e < ROWS*272
  int c8 = e % 272;
  int r = e / 272;
  int c = c8 * 8;
  int b = r >> 11, t = r & 2047;
  float4 w[8];
  float a[8];
#pragma unroll
  for (int j = 0; j < 8; ++j) {
    w[j] = *(const float4*)&cw[(c + j) * 4];
    a[j] = cb[c + j];
  }
  const u16* base = xbc + (size_t)(b << 11) * CONVD + c;
#pragma unroll
  for (int k = 0; k < 4; ++k) {
    int tt = t - 3 + k;
    if (tt >= 0) {
      ushort8 v = *(const ushort8*)(base + (size_t)tt * CONVD);
#pragma unroll
      for (int j = 0; j < 8; ++j) a[j] += bf2f(v[j]) * ((const float*)&w[j])[k];
    }
  }
  ushort8 o;
#pragma unroll
  for (int j = 0; j < 8; ++j) {
    float s = a[j] * (1.f / (1.f + expf(-a[j])));
    o[j] = f2bf(s);
  }
  if (c8 < 256) *(ushort8*)(xc + (size_t)r * DINNER + c) = o;
  else if (c8 < 264) *(ushort8*)(bm + (size_t)r * 64 + (c - DINNER)) = o;
  else *(ushort8*)(cm + (size_t)r * 64 + (c - DINNER - 64)) = o;
}

// ---------------- fused SSD scan v2: 8 waves, one block per (dir, batch, head) ----------------
__global__ __launch_bounds__(512) void k_ssd(const u16* __restrict__ xc,
                                             const u16* __restrict__ bmat,
                                             const u16* __restrict__ cmat,
                                             const float* __restrict__ dtp,
                                             const float* __restrict__ alog,
                                             u16* __restrict__ y0, u16* __restrict__ y1) {
  const int h = blockIdx.x & 31;
  const int grp = blockIdx.x >> 5;  // 0..7
  const int dir = grp >> 2;
  const int bt = grp & 3;
  const int tid = threadIdx.x, wave = tid >> 6, lane = tid & 63;
  const int lq = wave >> 1, wh = wave & 1;
  const int lr = lane & 15, lg = lane >> 4;
  const float Ah = -expf(alog[h]);

  __shared__ u16 sB[64][72];    // [s][n]
  __shared__ u16 sC[64][72];    // [s][n]
  __shared__ u16 sXM[64][72];   // staged X [s][p]; reused as M [l][s] after transpose
  __shared__ u16 sXT[64][72];   // X^T [p][s]
  __shared__ u16 sBT[64][72];   // B^T [n][s]
  __shared__ u16 sSb[64][72];   // bf16 shadow of state [p][n]
  __shared__ float sS[64][68];  // f32 state accumulator [p][n]
  __shared__ float sAc[64], sEA[64], sSc[64], sDt[64];

  for (int i = tid; i < 64 * 64; i += 512) {
    sS[i >> 6][i & 63] = 0.f;
    sSb[i >> 6][i & 63] = 0;
  }

  const int srow = tid >> 3, q8 = (tid & 7) * 8;

  auto rowOf = [&](int c) {
    int tdir = c * 64 + srow;
    return bt * LSEQ + (dir ? (LSEQ - 1 - tdir) : tdir);
  };

  int rg = rowOf(0);
  ushort8 rB = *(const ushort8*)(bmat + (size_t)rg * 64 + q8);
  ushort8 rC = *(const ushort8*)(cmat + (size_t)rg * 64 + q8);
  ushort8 rX = *(const ushort8*)(xc + (size_t)rg * DINNER + h * 64 + q8);

  for (int c = 0; c < NCHUNK; ++c) {
    // ---- stage (regs -> LDS) ----
    *(ushort8*)&sB[srow][q8] = rB;
    *(ushort8*)&sC[srow][q8] = rC;
    *(ushort8*)&sXM[srow][q8] = rX;
    __syncthreads();  // bar1

    // ---- transpose X, B (wave reads rows w*8..w*8+7, lane = column) + dt scan ----
    {
      ushort8 vx, vb;
#pragma unroll
      for (int i = 0; i < 8; ++i) {
        vx[i] = sXM[wave * 8 + i][lane];
        vb[i] = sB[wave * 8 + i][lane];
      }
      *(ushort8*)&sXT[lane][wave * 8] = vx;
      *(ushort8*)&sBT[lane][wave * 8] = vb;
    }
    if (wave == 0) {
      int s = lane;
      float dv = dtp[((size_t)grp * LSEQ + c * 64 + s) * NH + h];
      float a = dv * Ah;
      float x = a;
#pragma unroll
      for (int d = 1; d < 64; d <<= 1) {
        float y = __shfl_up(x, d);
        if (s >= d) x += y;
      }
      float tot = __shfl(x, 63);
      sAc[s] = x;
      sEA[s] = expf(x);
      sSc[s] = expf(tot - x) * dv;
      sDt[s] = dv;
    }
    __syncthreads();  // bar2

    // ---- early-issue next chunk's global loads (land during PA/PB) ----
    if (c + 1 < NCHUNK) {
      int rg2 = rowOf(c + 1);
      rB = *(const ushort8*)(bmat + (size_t)rg2 * 64 + q8);
      rC = *(const ushort8*)(cmat + (size_t)rg2 * 64 + q8);
      rX = *(const ushort8*)(xc + (size_t)rg2 * DINNER + h * 64 + q8);
    }

    // ---- PA: G = C@B^T -> M (into sXM); Yoff = C @ sSb^T ----
    f32x4 acc_y[2] = {};
    {
      f32x4 acc_g[2] = {};
#pragma unroll
      for (int ks = 0; ks < 2; ++ks) {
        int kof = ks * 32 + lg * 8;
        short8 af = *(const short8*)&sC[lq * 16 + lr][kof];
#pragma unroll
        for (int nt = 0; nt < 2; ++nt) {
          short8 bf = *(const short8*)&sB[wh * 32 + nt * 16 + lr][kof];
          acc_g[nt] = mfma16(af, bf, acc_g[nt]);
        }
      }
#pragma unroll
      for (int ks = 0; ks < 2; ++ks) {
        int kof = ks * 32 + lg * 8;
        short8 af = *(const short8*)&sC[lq * 16 + lr][kof];
#pragma unroll
        for (int nt = 0; nt < 2; ++nt) {
          short8 bf = *(const short8*)&sSb[wh * 32 + nt * 16 + lr][kof];
          acc_y[nt] = mfma16(af, bf, acc_y[nt]);
        }
      }
#pragma unroll
      for (int nt = 0; nt < 2; ++nt)
#pragma unroll
        for (int rr = 0; rr < 4; ++rr) {
          int l = lq * 16 + lg * 4 + rr;
          int s = wh * 32 + nt * 16 + lr;
          float g = acc_g[nt][rr];
          float m = (l >= s) ? g * sDt[s] * expf(sAc[l] - sAc[s]) : 0.f;
          sXM[l][s] = f2bf(m);
        }
    }
    __syncthreads();  // bar3

    // ---- PB: Y = Yoff*exp(Ac) + M@X^T; store; S update ----
#pragma unroll
    for (int nt = 0; nt < 2; ++nt)
#pragma unroll
      for (int rr = 0; rr < 4; ++rr) acc_y[nt][rr] *= sEA[lq * 16 + lg * 4 + rr];
#pragma unroll
    for (int ks = 0; ks < 2; ++ks) {
      int kof = ks * 32 + lg * 8;
      short8 af = *(const short8*)&sXM[lq * 16 + lr][kof];
#pragma unroll
      for (int nt = 0; nt < 2; ++nt) {
        short8 bf = *(const short8*)&sXT[wh * 32 + nt * 16 + lr][kof];
        acc_y[nt] = mfma16(af, bf, acc_y[nt]);
      }
    }
#pragma unroll
    for (int nt = 0; nt < 2; ++nt)
#pragma unroll
      for (int rr = 0; rr < 4; ++rr) {
        int l = lq * 16 + lg * 4 + rr;
        int p = wh * 32 + nt * 16 + lr;
        int tg = c * 64 + l;
        if (tg <= LSEQ - 2) {
          float v = acc_y[nt][rr];
          if (dir == 0)
            y0[((size_t)bt * LSEQ + tg + 1) * DINNER + h * 64 + p] = f2bf(v);
          else
            y1[((size_t)bt * LSEQ + (LSEQ - 2 - tg)) * DINNER + h * 64 + p] = f2bf(v);
        }
      }
    if (c == 0 && tid < 64) {
      if (dir == 0)
        y0[((size_t)bt * LSEQ) * DINNER + h * 64 + tid] = 0;
      else
        y1[((size_t)bt * LSEQ + (LSEQ - 1)) * DINNER + h * 64 + tid] = 0;
    }
    // chunk state: S = lam*S + (X*w)^T @ B
    {
      f32x4 acc_s[2] = {};
#pragma unroll
      for (int ks = 0; ks < 2; ++ks) {
        int kof = ks * 32 + lg * 8;
        ushort8 xr = *(const ushort8*)&sXT[lq * 16 + lr][kof];
        short8 af;
#pragma unroll
        for (int e = 0; e < 8; ++e) af[e] = (short)f2bf(bf2f(xr[e]) * sSc[kof + e]);
#pragma unroll
        for (int nt = 0; nt < 2; ++nt) {
          short8 bf = *(const short8*)&sBT[wh * 32 + nt * 16 + lr][kof];
          acc_s[nt] = mfma16(af, bf, acc_s[nt]);
        }
      }
      float lam = sEA[63];
#pragma unroll
      for (int nt = 0; nt < 2; ++nt)
#pragma unroll
        for (int rr = 0; rr < 4; ++rr) {
          int p = lq * 16 + lg * 4 + rr;
          int n = wh * 32 + nt * 16 + lr;
          float ns = lam * sS[p][n] + acc_s[nt][rr];
          sS[p][n] = ns;
          sSb[p][n] = f2bf(ns);
        }
    }
    __syncthreads();  // bar4
  }
}

// ---------------- Deff = x @ fc_D_w^T + D  (MFMA, split-K, 32 rows/block) ----------------
__global__ __launch_bounds__(256) void k_deff(const u16* __restrict__ xcv,
                                              const u16* __restrict__ fwb,
                                              const float* __restrict__ Dv,
                                              float* __restrict__ deff) {
  __shared__ float red[2][64][8];
  const int tid = threadIdx.x, wave = tid >> 6, lane = tid & 63;
  const int lr = lane & 15, lg = lane >> 4;
  const int rowg = wave & 1;
  const int kg = wave >> 1;
  const int rb = blockIdx.x * 32 + rowg * 16;
  const u16* xrow = xcv + (size_t)(rb + lr) * DINNER + kg * 1024 + lg * 8;
  const u16* f0 = fwb + (size_t)lr * DINNER + kg * 1024 + lg * 8;
  const u16* f1 = fwb + (size_t)(16 + lr) * DINNER + kg * 1024 + lg * 8;
  f32x4 a0 = {}, a1 = {};
  for (int k = 0; k < 1024; k += 32) {
    short8 bf = *(const short8*)(xrow + k);
    short8 af0 = *(const short8*)(f0 + k);
    short8 af1 = *(const short8*)(f1 + k);
    a0 = mfma16(af0, bf, a0);
    a1 = mfma16(af1, bf, a1);
  }
  if (kg == 1) {
#pragma unroll
    for (int rr = 0; rr < 4; ++rr) {
      red[rowg][lane][rr] = a0[rr];
      red[rowg][lane][4 + rr] = a1[rr];
    }
  }
  __syncthreads();
  if (kg == 0) {
    float4 o0, o1;
#pragma unroll
    for (int rr = 0; rr < 4; ++rr) {
      ((float*)&o0)[rr] = a0[rr] + red[rowg][lane][rr] + Dv[lg * 4 + rr];
      ((float*)&o1)[rr] = a1[rr] + red[rowg][lane][4 + rr] + Dv[16 + lg * 4 + rr];
    }
    *(float4*)&deff[(size_t)(rb + lr) * NH + lg * 4] = o0;
    *(float4*)&deff[(size_t)(rb + lr) * NH + 16 + lg * 4] = o1;
  }
}

// ---------------- gating: yn = rmsnorm((y0 + y1 + x*Deff) * silu(z)) * gnw ----------------
__global__ __launch_bounds__(256) void k_gate(const u16* __restrict__ yb0,
                                              const u16* __restrict__ yb1,
                                              const u16* __restrict__ xcv,
                                              const float* __restrict__ deff,
                                              const u16* __restrict__ zb,
                                              const float* __restrict__ gnw,
                                              u16* __restrict__ yn) {
  int row = blockIdx.x, t = threadIdx.x;
  size_t base = (size_t)row * DINNER + t * 8;
  ushort8 y0v = *(const ushort8*)(yb0 + base);
  ushort8 y1v = *(const ushort8*)(yb1 + base);
  ushort8 xv = *(const ushort8*)(xcv + base);
  ushort8 zv = *(const ushort8*)(zb + base);
  float de = deff[row * NH + (t >> 3)];
  float g[8];
  float ss = 0.f;
#pragma unroll
  for (int j = 0; j < 8; ++j) {
    float y = bf2f(y0v[j]) + bf2f(y1v[j]) + bf2f(xv[j]) * de;
    float z = bf2f(zv[j]);
    float gg = y * (z / (1.f + expf(-z)));
    g[j] = gg;
    ss += gg * gg;
  }
  for (int m = 32; m; m >>= 1) ss += __shfl_xor(ss, m);
  __shared__ float wsum[4];
  if ((t & 63) == 0) wsum[t >> 6] = ss;
  __syncthreads();
  float tot = wsum[0] + wsum[1] + wsum[2] + wsum[3];
  float rinv = rsqrtf(tot * (1.0f / DINNER) + 1e-5f);
  u32 w0 = (u32)f2bf(g[0] * rinv * gnw[t * 8 + 0]) | ((u32)f2bf(g[1] * rinv * gnw[t * 8 + 1]) << 16);
  u32 w1 = (u32)f2bf(g[2] * rinv * gnw[t * 8 + 2]) | ((u32)f2bf(g[3] * rinv * gnw[t * 8 + 3]) << 16);
  u32 w2 = (u32)f2bf(g[4] * rinv * gnw[t * 8 + 4]) | ((u32)f2bf(g[5] * rinv * gnw[t * 8 + 5]) << 16);
  u32 w3 = (u32)f2bf(g[6] * rinv * gnw[t * 8 + 6]) | ((u32)f2bf(g[7] * rinv * gnw[t * 8 + 7]) << 16);
  *(uint4*)(yn + base) = make_uint4(w0, w1, w2, w3);
}

extern "C" void kernel_launch(void* const* d_in, const int* in_sizes, int n_in,
                              void* d_out, int out_size, void* d_ws, size_t ws_size,
                              hipStream_t stream) {
  (void)in_sizes; (void)n_in; (void)out_size; (void)ws_size;
  const float* hid = (const float*)d_in[0];
  const float* resin = (const float*)d_in[1];
  const float* nw = (const float*)d_in[2];
  const float* w1 = (const float*)d_in[3];
  const float* cw = (const float*)d_in[4];
  const float* cb = (const float*)d_in[5];
  const float* dtb = (const float*)d_in[6];
  const float* alog = (const float*)d_in[7];
  const float* Dv = (const float*)d_in[8];
  const float* fcw = (const float*)d_in[9];
  const float* gnw = (const float*)d_in[10];
  const float* w2 = (const float*)d_in[11];
  float* out = (float*)d_out;
  float* resout = out + (size_t)ROWS * DMODEL;

  char* ws = (char*)d_ws;
  size_t o = 0;
  auto alloc = [&](size_t bytes) {
    char* p = ws + o;
    o += (bytes + 255) & ~(size_t)255;
    return p;
  };
  u16* W1b = (u16*)alloc((size_t)DIP_PAD * DMODEL * 2);  // 8.9 MB (reused for W2b)
  u16* HN = (u16*)alloc((size_t)ROWS * DMODEL * 2);      // 16.8 MB (reused for YN)
  u16* XBC = (u16*)alloc((size_t)ROWS * CONVD * 2);      // 35.7 MB (reused for YB0)
  u16* ZB = (u16*)alloc((size_t)ROWS * DINNER * 2);      // 33.6 MB
  u16* XC = (u16*)alloc((size_t)ROWS * DINNER * 2);      // 33.6 MB
  u16* BM = (u16*)alloc((size_t)ROWS * 64 * 2);          // 1 MB
  u16* CM = (u16*)alloc((size_t)ROWS * 64 * 2);          // 1 MB
  float* DT = (float*)alloc((size_t)8 * LSEQ * NH * 4);  // 2 MB
  float* DE = (float*)alloc((size_t)ROWS * NH * 4);      // 1 MB
  u16* FWB = (u16*)alloc((size_t)NH * DINNER * 2);       // 128 KB
  u16* YB0 = XBC;
  u16* YB1 = (u16*)out;  // out region (33.55 MB) is dead until final GEMM
  u16* W2b = W1b;
  u16* YN = HN;

  k_cast<<<(DIP * DMODEL) / 1024, 256, 0, stream>>>(w1, W1b);
  k_addnorm<<<ROWS, 256, 0, stream>>>(hid, resin, nw, resout, HN);
  // in_proj: M=8192 (64 tiles of 128), N=4352 (17 tiles of 256), K=1024
  k_gemm<0><<<64 * 17, 512, 0, stream>>>(HN, W1b, DMODEL, 17, nullptr, ZB, XBC, DT, dtb);
  k_conv<<<(ROWS * 272) / 256, 256, 0, stream>>>(XBC, cw, cb, XC, BM, CM);
  k_ssd<<<256, 512, 0, stream>>>(XC, BM, CM, DT, alog, YB0, YB1);
  k_cast<<<(DMODEL * DINNER) / 1024, 256, 0, stream>>>(w2, W2b);
  k_cast<<<(NH * DINNER) / 1024, 256, 0, stream>>>(fcw, FWB);
  k_deff<<<ROWS / 32, 256, 0, stream>>>(XC, FWB, Dv, DE);
  k_gate<<<ROWS, 256, 0, stream>>>(YB0, YB1, XC, DE, ZB, gnw, YN);
  // out_proj: M=8192 (64 tiles), N=1024 (4 tiles of 256), K=2048
  k_gemm<1><<<64 * 4, 512, 0, stream>>>(YN, W2b, DINNER, 4, out, nullptr, nullptr, nullptr,
                                        nullptr);
}

// Round 10
// 478.610 us; speedup vs baseline: 1.0586x; 1.0586x over previous
//
#include <hip/hip_runtime.h>

typedef __attribute__((ext_vector_type(4))) float f32x4;
typedef __attribute__((ext_vector_type(8))) short short8;
typedef __attribute__((ext_vector_type(8))) unsigned short ushort8;
typedef unsigned short u16;
typedef unsigned int u32;

#define DMODEL 1024
#define DINNER 2048
#define NH     32
#define DIP    4288
#define DIP_PAD 4352
#define CONVD  2176
#define LSEQ   2048
#define ROWS   8192
#define NCHUNK 32

static __device__ __forceinline__ float bf2f(u16 u) {
  u32 x = ((u32)u) << 16;
  return __builtin_bit_cast(float, x);
}
static __device__ __forceinline__ u16 f2bf(float f) {
  u32 x = __builtin_bit_cast(u32, f);
  x += 0x7fffu + ((x >> 16) & 1u);
  return (u16)(x >> 16);
}
static __device__ __forceinline__ f32x4 mfma16(short8 a, short8 b, f32x4 c) {
  return __builtin_amdgcn_mfma_f32_16x16x32_bf16(a, b, c, 0, 0, 0);
}

#define GLDS(gp, lp)                                                     \
  __builtin_amdgcn_global_load_lds(                                     \
      (const __attribute__((address_space(1))) void*)(gp),              \
      (__attribute__((address_space(3))) void*)(lp), 16, 0, 0)

// ---------------- f32 -> bf16 weight cast ----------------
__global__ __launch_bounds__(256) void k_cast(const float* __restrict__ s, u16* __restrict__ d) {
  size_t i = ((size_t)blockIdx.x * 256 + threadIdx.x) * 4;
  float4 v = *(const float4*)(s + i);
  u32 lo = (u32)f2bf(v.x) | ((u32)f2bf(v.y) << 16);
  u32 hi = (u32)f2bf(v.z) | ((u32)f2bf(v.w) << 16);
  *(uint2*)(d + i) = make_uint2(lo, hi);
}

// ---------------- res = h + r ; hnorm = rmsnorm(res)*w (bf16) ----------------
__global__ __launch_bounds__(256) void k_addnorm(const float* __restrict__ h,
                                                 const float* __restrict__ r,
                                                 const float* __restrict__ nw,
                                                 float* __restrict__ res,
                                                 u16* __restrict__ hn) {
  int row = blockIdx.x, t = threadIdx.x;
  const float4* hp = (const float4*)(h + (size_t)row * DMODEL);
  const float4* rp = (const float4*)(r + (size_t)row * DMODEL);
  float4 a = hp[t], b = rp[t];
  float4 s;
  s.x = a.x + b.x; s.y = a.y + b.y; s.z = a.z + b.z; s.w = a.w + b.w;
  ((float4*)(res + (size_t)row * DMODEL))[t] = s;
  float ss = s.x * s.x + s.y * s.y + s.z * s.z + s.w * s.w;
  for (int m = 32; m; m >>= 1) ss += __shfl_xor(ss, m);
  __shared__ float wsum[4];
  if ((t & 63) == 0) wsum[t >> 6] = ss;
  __syncthreads();
  float tot = wsum[0] + wsum[1] + wsum[2] + wsum[3];
  float rinv = rsqrtf(tot * (1.0f / DMODEL) + 1e-5f);
  float4 w4 = ((const float4*)nw)[t];
  u32 lo = (u32)f2bf(s.x * rinv * w4.x) | ((u32)f2bf(s.y * rinv * w4.y) << 16);
  u32 hi = (u32)f2bf(s.z * rinv * w4.z) | ((u32)f2bf(s.w * rinv * w4.w) << 16);
  *(uint2*)(hn + (size_t)row * DMODEL + t * 4) = make_uint2(lo, hi);
}

// ---------------- bf16 MFMA GEMM: 128x256 tile, 8 waves, BK=64 ----------------
// Single-barrier 2-phase loop (round-8 schedule, proven fastest):
//   STAGE(t+1) -> ds_read buf[t] + MFMA (interleaved, waves drift) -> vmcnt(0)
//   -> barrier. Loads get the full compute phase to land; LDS-read and MFMA
//   pipes overlap across waves.
// XCD supertile remap (round-9, proven: FETCH 219->75 MB): xcd = bid%8 owns an
// 8-brow band; within it 8x4 supertiles (A 2MB + B 2MB fits the 4MB XCD L2).
template <int MODE>
__global__ __launch_bounds__(512) void k_gemm(const u16* __restrict__ A,
                                              const u16* __restrict__ Bw, int K, int nN,
                                              float* __restrict__ outf,
                                              u16* __restrict__ zb, u16* __restrict__ xb,
                                              float* __restrict__ dtp,
                                              const float* __restrict__ dt_bias) {
  constexpr int ABY = 128 * 64 * 2;   // 16 KB A tile
  constexpr int BBY = 256 * 64 * 2;   // 32 KB B tile
  constexpr int TB = ABY + BBY;       // 48 KB per buffer
  __shared__ char lds[2 * TB];        // 96 KB

  const int tid = threadIdx.x, wave = tid >> 6, lane = tid & 63;
  const int wm = wave >> 2, wn = wave & 3;
  const int lr = lane & 15, lg = lane >> 4;

  // XCD supertile remap: gridDim.x % 8 == 0; brows-per-XCD = (gridDim.x/8)/nN = 8.
  const int xcd = blockIdx.x & 7;
  const int l = blockIdx.x >> 3;
  const int nstFull = nN >> 2;
  int brl, bc;
  if (l < (nstFull << 5)) {
    int st = l >> 5, off = l & 31;
    brl = off & 7;
    bc = (st << 2) + (off >> 3);
  } else {
    int rem = l - (nstFull << 5);
    brl = rem & 7;
    bc = (nstFull << 2) + (rem >> 3);
  }
  const int brow = (xcd * 8 + brl) * 128;
  const int bcol = bc * 256;
  const int NK = K >> 6;

  size_t srcA[2], srcB[4];
#pragma unroll
  for (int g = 0; g < 2; ++g) {
    int d = g * 8192 + tid * 16;
    int s = d ^ (((d >> 7) & 7) << 4);
    srcA[g] = (size_t)(brow + (s >> 7)) * K + ((s & 127) >> 1);
  }
#pragma unroll
  for (int g = 0; g < 4; ++g) {
    int d = g * 8192 + tid * 16;
    int s = d ^ (((d >> 7) & 7) << 4);
    srcB[g] = (size_t)(bcol + (s >> 7)) * K + ((s & 127) >> 1);
  }

  auto STAGE = [&](int buf, int kt) {
    char* base = lds + buf * TB;
    size_t koff = (size_t)kt * 64;
#pragma unroll
    for (int g = 0; g < 2; ++g)
      GLDS(A + srcA[g] + koff, base + g * 8192 + wave * 1024);
#pragma unroll
    for (int g = 0; g < 4; ++g)
      GLDS(Bw + srcB[g] + koff, base + ABY + g * 8192 + wave * 1024);
  };

  int offA[4][2], offB[4][2];
#pragma unroll
  for (int i = 0; i < 4; ++i)
#pragma unroll
    for (int ks = 0; ks < 2; ++ks) {
      int rA = wm * 64 + i * 16 + lr;
      offA[i][ks] = (rA * 128 + ks * 64 + lg * 16) ^ ((lr & 7) << 4);
      int rB = wn * 64 + i * 16 + lr;
      offB[i][ks] = ABY + ((rB * 128 + ks * 64 + lg * 16) ^ ((lr & 7) << 4));
    }

  f32x4 acc[4][4] = {};
  STAGE(0, 0);
  asm volatile("s_waitcnt vmcnt(0)" ::: "memory");
  __builtin_amdgcn_s_barrier();
  for (int t = 0; t < NK; ++t) {
    const int cur = t & 1;
    if (t + 1 < NK) STAGE(cur ^ 1, t + 1);
    const char* bb = lds + cur * TB;
    short8 af[4], bfr[4];
#pragma unroll
    for (int i = 0; i < 4; ++i) af[i] = *(const short8*)(bb + offA[i][0]);
#pragma unroll
    for (int j = 0; j < 4; ++j) bfr[j] = *(const short8*)(bb + offB[j][0]);
    __builtin_amdgcn_s_setprio(1);
#pragma unroll
    for (int i = 0; i < 4; ++i)
#pragma unroll
      for (int j = 0; j < 4; ++j) acc[i][j] = mfma16(af[i], bfr[j], acc[i][j]);
    __builtin_amdgcn_s_setprio(0);
#pragma unroll
    for (int i = 0; i < 4; ++i) af[i] = *(const short8*)(bb + offA[i][1]);
#pragma unroll
    for (int j = 0; j < 4; ++j) bfr[j] = *(const short8*)(bb + offB[j][1]);
    __builtin_amdgcn_s_setprio(1);
#pragma unroll
    for (int i = 0; i < 4; ++i)
#pragma unroll
      for (int j = 0; j < 4; ++j) acc[i][j] = mfma16(af[i], bfr[j], acc[i][j]);
    __builtin_amdgcn_s_setprio(0);
    if (t + 1 < NK) {
      asm volatile("s_waitcnt vmcnt(0)" ::: "memory");
      __builtin_amdgcn_s_barrier();
    }
  }

  const int mb = brow + wm * 64 + lg * 4;
  const int nb = bcol + wn * 64 + lr;
#pragma unroll
  for (int i = 0; i < 4; ++i)
#pragma unroll
    for (int j = 0; j < 4; ++j)
#pragma unroll
      for (int rr = 0; rr < 4; ++rr) {
        int m = mb + i * 16 + rr;
        int n = nb + j * 16;
        float v = acc[i][j][rr];
        if constexpr (MODE == 1) {
          outf[(size_t)m * 1024 + n] = v;
        } else {
          if (n < DINNER) {
            zb[(size_t)m * DINNER + n] = f2bf(v);
          } else if (n < DINNER + CONVD) {
            xb[(size_t)m * CONVD + (n - DINNER)] = f2bf(v);
          } else if (n < DIP) {
            int h2 = n - (DINNER + CONVD);  // 0..63
            float uu = v + dt_bias[h2 & 31];
            float sp = (uu > 20.f) ? uu : log1pf(expf(uu));
            int bb2 = m >> 11, tt = m & 2047;
            int obb = bb2, ot = tt;
            if (h2 >= 32) { obb = bb2 + 4; ot = 2047 - tt; }
            dtp[((size_t)(obb << 11) + ot) * NH + (h2 & 31)] = sp;
          }
        }
      }
}

// ---------------- depthwise causal conv (k=4) + SiLU, 8 chans/thread ----------------
__global__ __launch_bounds__(256) void k_conv(const u16* __restrict__ xbc,
                                              const float* __restrict__ cw,
                                              const float* __restrict__ cb,
                                              u16* __restrict__ xc, u16* __restrict__ bm,
                                              u16* __restrict__ cm) {
  int e = blockIdx.x * 256 + threadIdx.x;  // e < ROWS*272
  int c8 = e % 272;
  int r = e / 272;
  int c = c8 * 8;
  int b = r >> 11, t = r & 2047;
  float4 w[8];
  float a[8];
#pragma unroll
  for (int j = 0; j < 8; ++j) {
    w[j] = *(const float4*)&cw[(c + j) * 4];
    a[j] = cb[c + j];
  }
  const u16* base = xbc + (size_t)(b << 11) * CONVD + c;
#pragma unroll
  for (int k = 0; k < 4; ++k) {
    int tt = t - 3 + k;
    if (tt >= 0) {
      ushort8 v = *(const ushort8*)(base + (size_t)tt * CONVD);
#pragma unroll
      for (int j = 0; j < 8; ++j) a[j] += bf2f(v[j]) * ((const float*)&w[j])[k];
    }
  }
  ushort8 o;
#pragma unroll
  for (int j = 0; j < 8; ++j) {
    float s = a[j] * (1.f / (1.f + expf(-a[j])));
    o[j] = f2bf(s);
  }
  if (c8 < 256) *(ushort8*)(xc + (size_t)r * DINNER + c) = o;
  else if (c8 < 264) *(ushort8*)(bm + (size_t)r * 64 + (c - DINNER)) = o;
  else *(ushort8*)(cm + (size_t)r * 64 + (c - DINNER - 64)) = o;
}

// ---------------- fused SSD scan v2: 8 waves, one block per (dir, batch, head) ----------------
__global__ __launch_bounds__(512) void k_ssd(const u16* __restrict__ xc,
                                             const u16* __restrict__ bmat,
                                             const u16* __restrict__ cmat,
                                             const float* __restrict__ dtp,
                                             const float* __restrict__ alog,
                                             u16* __restrict__ y0, u16* __restrict__ y1) {
  const int h = blockIdx.x & 31;
  const int grp = blockIdx.x >> 5;  // 0..7
  const int dir = grp >> 2;
  const int bt = grp & 3;
  const int tid = threadIdx.x, wave = tid >> 6, lane = tid & 63;
  const int lq = wave >> 1, wh = wave & 1;
  const int lr = lane & 15, lg = lane >> 4;
  const float Ah = -expf(alog[h]);

  __shared__ u16 sB[64][72];    // [s][n]
  __shared__ u16 sC[64][72];    // [s][n]
  __shared__ u16 sXM[64][72];   // staged X [s][p]; reused as M [l][s] after transpose
  __shared__ u16 sXT[64][72];   // X^T [p][s]
  __shared__ u16 sBT[64][72];   // B^T [n][s]
  __shared__ u16 sSb[64][72];   // bf16 shadow of state [p][n]
  __shared__ float sS[64][68];  // f32 state accumulator [p][n]
  __shared__ float sAc[64], sEA[64], sSc[64], sDt[64];

  for (int i = tid; i < 64 * 64; i += 512) {
    sS[i >> 6][i & 63] = 0.f;
    sSb[i >> 6][i & 63] = 0;
  }

  const int srow = tid >> 3, q8 = (tid & 7) * 8;

  auto rowOf = [&](int c) {
    int tdir = c * 64 + srow;
    return bt * LSEQ + (dir ? (LSEQ - 1 - tdir) : tdir);
  };

  int rg = rowOf(0);
  ushort8 rB = *(const ushort8*)(bmat + (size_t)rg * 64 + q8);
  ushort8 rC = *(const ushort8*)(cmat + (size_t)rg * 64 + q8);
  ushort8 rX = *(const ushort8*)(xc + (size_t)rg * DINNER + h * 64 + q8);

  for (int c = 0; c < NCHUNK; ++c) {
    // ---- stage (regs -> LDS) ----
    *(ushort8*)&sB[srow][q8] = rB;
    *(ushort8*)&sC[srow][q8] = rC;
    *(ushort8*)&sXM[srow][q8] = rX;
    __syncthreads();  // bar1

    // ---- transpose X, B (wave reads rows w*8..w*8+7, lane = column) + dt scan ----
    {
      ushort8 vx, vb;
#pragma unroll
      for (int i = 0; i < 8; ++i) {
        vx[i] = sXM[wave * 8 + i][lane];
        vb[i] = sB[wave * 8 + i][lane];
      }
      *(ushort8*)&sXT[lane][wave * 8] = vx;
      *(ushort8*)&sBT[lane][wave * 8] = vb;
    }
    if (wave == 0) {
      int s = lane;
      float dv = dtp[((size_t)grp * LSEQ + c * 64 + s) * NH + h];
      float a = dv * Ah;
      float x = a;
#pragma unroll
      for (int d = 1; d < 64; d <<= 1) {
        float y = __shfl_up(x, d);
        if (s >= d) x += y;
      }
      float tot = __shfl(x, 63);
      sAc[s] = x;
      sEA[s] = expf(x);
      sSc[s] = expf(tot - x) * dv;
      sDt[s] = dv;
    }
    __syncthreads();  // bar2

    // ---- early-issue next chunk's global loads (land during PA/PB) ----
    if (c + 1 < NCHUNK) {
      int rg2 = rowOf(c + 1);
      rB = *(const ushort8*)(bmat + (size_t)rg2 * 64 + q8);
      rC = *(const ushort8*)(cmat + (size_t)rg2 * 64 + q8);
      rX = *(const ushort8*)(xc + (size_t)rg2 * DINNER + h * 64 + q8);
    }

    // ---- PA: G = C@B^T -> M (into sXM); Yoff = C @ sSb^T ----
    f32x4 acc_y[2] = {};
    {
      f32x4 acc_g[2] = {};
#pragma unroll
      for (int ks = 0; ks < 2; ++ks) {
        int kof = ks * 32 + lg * 8;
        short8 af = *(const short8*)&sC[lq * 16 + lr][kof];
#pragma unroll
        for (int nt = 0; nt < 2; ++nt) {
          short8 bf = *(const short8*)&sB[wh * 32 + nt * 16 + lr][kof];
          acc_g[nt] = mfma16(af, bf, acc_g[nt]);
        }
      }
#pragma unroll
      for (int ks = 0; ks < 2; ++ks) {
        int kof = ks * 32 + lg * 8;
        short8 af = *(const short8*)&sC[lq * 16 + lr][kof];
#pragma unroll
        for (int nt = 0; nt < 2; ++nt) {
          short8 bf = *(const short8*)&sSb[wh * 32 + nt * 16 + lr][kof];
          acc_y[nt] = mfma16(af, bf, acc_y[nt]);
        }
      }
#pragma unroll
      for (int nt = 0; nt < 2; ++nt)
#pragma unroll
        for (int rr = 0; rr < 4; ++rr) {
          int l = lq * 16 + lg * 4 + rr;
          int s = wh * 32 + nt * 16 + lr;
          float g = acc_g[nt][rr];
          float m = (l >= s) ? g * sDt[s] * expf(sAc[l] - sAc[s]) : 0.f;
          sXM[l][s] = f2bf(m);
        }
    }
    __syncthreads();  // bar3

    // ---- PB: Y = Yoff*exp(Ac) + M@X^T; store; S update ----
#pragma unroll
    for (int nt = 0; nt < 2; ++nt)
#pragma unroll
      for (int rr = 0; rr < 4; ++rr) acc_y[nt][rr] *= sEA[lq * 16 + lg * 4 + rr];
#pragma unroll
    for (int ks = 0; ks < 2; ++ks) {
      int kof = ks * 32 + lg * 8;
      short8 af = *(const short8*)&sXM[lq * 16 + lr][kof];
#pragma unroll
      for (int nt = 0; nt < 2; ++nt) {
        short8 bf = *(const short8*)&sXT[wh * 32 + nt * 16 + lr][kof];
        acc_y[nt] = mfma16(af, bf, acc_y[nt]);
      }
    }
#pragma unroll
    for (int nt = 0; nt < 2; ++nt)
#pragma unroll
      for (int rr = 0; rr < 4; ++rr) {
        int l = lq * 16 + lg * 4 + rr;
        int p = wh * 32 + nt * 16 + lr;
        int tg = c * 64 + l;
        if (tg <= LSEQ - 2) {
          float v = acc_y[nt][rr];
          if (dir == 0)
            y0[((size_t)bt * LSEQ + tg + 1) * DINNER + h * 64 + p] = f2bf(v);
          else
            y1[((size_t)bt * LSEQ + (LSEQ - 2 - tg)) * DINNER + h * 64 + p] = f2bf(v);
        }
      }
    if (c == 0 && tid < 64) {
      if (dir == 0)
        y0[((size_t)bt * LSEQ) * DINNER + h * 64 + tid] = 0;
      else
        y1[((size_t)bt * LSEQ + (LSEQ - 1)) * DINNER + h * 64 + tid] = 0;
    }
    // chunk state: S = lam*S + (X*w)^T @ B
    {
      f32x4 acc_s[2] = {};
#pragma unroll
      for (int ks = 0; ks < 2; ++ks) {
        int kof = ks * 32 + lg * 8;
        ushort8 xr = *(const ushort8*)&sXT[lq * 16 + lr][kof];
        short8 af;
#pragma unroll
        for (int e = 0; e < 8; ++e) af[e] = (short)f2bf(bf2f(xr[e]) * sSc[kof + e]);
#pragma unroll
        for (int nt = 0; nt < 2; ++nt) {
          short8 bf = *(const short8*)&sBT[wh * 32 + nt * 16 + lr][kof];
          acc_s[nt] = mfma16(af, bf, acc_s[nt]);
        }
      }
      float lam = sEA[63];
#pragma unroll
      for (int nt = 0; nt < 2; ++nt)
#pragma unroll
        for (int rr = 0; rr < 4; ++rr) {
          int p = lq * 16 + lg * 4 + rr;
          int n = wh * 32 + nt * 16 + lr;
          float ns = lam * sS[p][n] + acc_s[nt][rr];
          sS[p][n] = ns;
          sSb[p][n] = f2bf(ns);
        }
    }
    __syncthreads();  // bar4
  }
}

// ---------------- Deff = x @ fc_D_w^T + D  (MFMA, split-K, 32 rows/block) ----------------
__global__ __launch_bounds__(256) void k_deff(const u16* __restrict__ xcv,
                                              const u16* __restrict__ fwb,
                                              const float* __restrict__ Dv,
                                              float* __restrict__ deff) {
  __shared__ float red[2][64][8];
  const int tid = threadIdx.x, wave = tid >> 6, lane = tid & 63;
  const int lr = lane & 15, lg = lane >> 4;
  const int rowg = wave & 1;
  const int kg = wave >> 1;
  const int rb = blockIdx.x * 32 + rowg * 16;
  const u16* xrow = xcv + (size_t)(rb + lr) * DINNER + kg * 1024 + lg * 8;
  const u16* f0 = fwb + (size_t)lr * DINNER + kg * 1024 + lg * 8;
  const u16* f1 = fwb + (size_t)(16 + lr) * DINNER + kg * 1024 + lg * 8;
  f32x4 a0 = {}, a1 = {};
  for (int k = 0; k < 1024; k += 32) {
    short8 bf = *(const short8*)(xrow + k);
    short8 af0 = *(const short8*)(f0 + k);
    short8 af1 = *(const short8*)(f1 + k);
    a0 = mfma16(af0, bf, a0);
    a1 = mfma16(af1, bf, a1);
  }
  if (kg == 1) {
#pragma unroll
    for (int rr = 0; rr < 4; ++rr) {
      red[rowg][lane][rr] = a0[rr];
      red[rowg][lane][4 + rr] = a1[rr];
    }
  }
  __syncthreads();
  if (kg == 0) {
    float4 o0, o1;
#pragma unroll
    for (int rr = 0; rr < 4; ++rr) {
      ((float*)&o0)[rr] = a0[rr] + red[rowg][lane][rr] + Dv[lg * 4 + rr];
      ((float*)&o1)[rr] = a1[rr] + red[rowg][lane][4 + rr] + Dv[16 + lg * 4 + rr];
    }
    *(float4*)&deff[(size_t)(rb + lr) * NH + lg * 4] = o0;
    *(float4*)&deff[(size_t)(rb + lr) * NH + 16 + lg * 4] = o1;
  }
}

// ---------------- gating: yn = rmsnorm((y0 + y1 + x*Deff) * silu(z)) * gnw ----------------
__global__ __launch_bounds__(256) void k_gate(const u16* __restrict__ yb0,
                                              const u16* __restrict__ yb1,
                                              const u16* __restrict__ xcv,
                                              const float* __restrict__ deff,
                                              const u16* __restrict__ zb,
                                              const float* __restrict__ gnw,
                                              u16* __restrict__ yn) {
  int row = blockIdx.x, t = threadIdx.x;
  size_t base = (size_t)row * DINNER + t * 8;
  ushort8 y0v = *(const ushort8*)(yb0 + base);
  ushort8 y1v = *(const ushort8*)(yb1 + base);
  ushort8 xv = *(const ushort8*)(xcv + base);
  ushort8 zv = *(const ushort8*)(zb + base);
  float de = deff[row * NH + (t >> 3)];
  float g[8];
  float ss = 0.f;
#pragma unroll
  for (int j = 0; j < 8; ++j) {
    float y = bf2f(y0v[j]) + bf2f(y1v[j]) + bf2f(xv[j]) * de;
    float z = bf2f(zv[j]);
    float gg = y * (z / (1.f + expf(-z)));
    g[j] = gg;
    ss += gg * gg;
  }
  for (int m = 32; m; m >>= 1) ss += __shfl_xor(ss, m);
  __shared__ float wsum[4];
  if ((t & 63) == 0) wsum[t >> 6] = ss;
  __syncthreads();
  float tot = wsum[0] + wsum[1] + wsum[2] + wsum[3];
  float rinv = rsqrtf(tot * (1.0f / DINNER) + 1e-5f);
  u32 w0 = (u32)f2bf(g[0] * rinv * gnw[t * 8 + 0]) | ((u32)f2bf(g[1] * rinv * gnw[t * 8 + 1]) << 16);
  u32 w1 = (u32)f2bf(g[2] * rinv * gnw[t * 8 + 2]) | ((u32)f2bf(g[3] * rinv * gnw[t * 8 + 3]) << 16);
  u32 w2 = (u32)f2bf(g[4] * rinv * gnw[t * 8 + 4]) | ((u32)f2bf(g[5] * rinv * gnw[t * 8 + 5]) << 16);
  u32 w3 = (u32)f2bf(g[6] * rinv * gnw[t * 8 + 6]) | ((u32)f2bf(g[7] * rinv * gnw[t * 8 + 7]) << 16);
  *(uint4*)(yn + base) = make_uint4(w0, w1, w2, w3);
}

extern "C" void kernel_launch(void* const* d_in, const int* in_sizes, int n_in,
                              void* d_out, int out_size, void* d_ws, size_t ws_size,
                              hipStream_t stream) {
  (void)in_sizes; (void)n_in; (void)out_size; (void)ws_size;
  const float* hid = (const float*)d_in[0];
  const float* resin = (const float*)d_in[1];
  const float* nw = (const float*)d_in[2];
  const float* w1 = (const float*)d_in[3];
  const float* cw = (const float*)d_in[4];
  const float* cb = (const float*)d_in[5];
  const float* dtb = (const float*)d_in[6];
  const float* alog = (const float*)d_in[7];
  const float* Dv = (const float*)d_in[8];
  const float* fcw = (const float*)d_in[9];
  const float* gnw = (const float*)d_in[10];
  const float* w2 = (const float*)d_in[11];
  float* out = (float*)d_out;
  float* resout = out + (size_t)ROWS * DMODEL;

  char* ws = (char*)d_ws;
  size_t o = 0;
  auto alloc = [&](size_t bytes) {
    char* p = ws + o;
    o += (bytes + 255) & ~(size_t)255;
    return p;
  };
  u16* W1b = (u16*)alloc((size_t)DIP_PAD * DMODEL * 2);  // 8.9 MB (reused for W2b)
  u16* HN = (u16*)alloc((size_t)ROWS * DMODEL * 2);      // 16.8 MB (reused for YN)
  u16* XBC = (u16*)alloc((size_t)ROWS * CONVD * 2);      // 35.7 MB (reused for YB0)
  u16* ZB = (u16*)alloc((size_t)ROWS * DINNER * 2);      // 33.6 MB
  u16* XC = (u16*)alloc((size_t)ROWS * DINNER * 2);      // 33.6 MB
  u16* BM = (u16*)alloc((size_t)ROWS * 64 * 2);          // 1 MB
  u16* CM = (u16*)alloc((size_t)ROWS * 64 * 2);          // 1 MB
  float* DT = (float*)alloc((size_t)8 * LSEQ * NH * 4);  // 2 MB
  float* DE = (float*)alloc((size_t)ROWS * NH * 4);      // 1 MB
  u16* FWB = (u16*)alloc((size_t)NH * DINNER * 2);       // 128 KB
  u16* YB0 = XBC;
  u16* YB1 = (u16*)out;  // out region (33.55 MB) is dead until final GEMM
  u16* W2b = W1b;
  u16* YN = HN;

  k_cast<<<(DIP * DMODEL) / 1024, 256, 0, stream>>>(w1, W1b);
  k_addnorm<<<ROWS, 256, 0, stream>>>(hid, resin, nw, resout, HN);
  // in_proj: M=8192 (64 tiles of 128), N=4352 (17 tiles of 256), K=1024
  k_gemm<0><<<64 * 17, 512, 0, stream>>>(HN, W1b, DMODEL, 17, nullptr, ZB, XBC, DT, dtb);
  k_conv<<<(ROWS * 272) / 256, 256, 0, stream>>>(XBC, cw, cb, XC, BM, CM);
  k_ssd<<<256, 512, 0, stream>>>(XC, BM, CM, DT, alog, YB0, YB1);
  k_cast<<<(DMODEL * DINNER) / 1024, 256, 0, stream>>>(w2, W2b);
  k_cast<<<(NH * DINNER) / 1024, 256, 0, stream>>>(fcw, FWB);
  k_deff<<<ROWS / 32, 256, 0, stream>>>(XC, FWB, Dv, DE);
  k_gate<<<ROWS, 256, 0, stream>>>(YB0, YB1, XC, DE, ZB, gnw, YN);
  // out_proj: M=8192 (64 tiles), N=1024 (4 tiles of 256), K=2048
  k_gemm<1><<<64 * 4, 512, 0, stream>>>(YN, W2b, DINNER, 4, out, nullptr, nullptr, nullptr,
                                        nullptr);
}

// Round 11
// 407.193 us; speedup vs baseline: 1.2443x; 1.1754x over previous
//
#include <hip/hip_runtime.h>

typedef __attribute__((ext_vector_type(4))) float f32x4;
typedef __attribute__((ext_vector_type(8))) short short8;
typedef __attribute__((ext_vector_type(8))) unsigned short ushort8;
typedef unsigned short u16;
typedef unsigned int u32;

#define DMODEL 1024
#define DINNER 2048
#define NH     32
#define DIP    4288
#define DIP_PAD 4352
#define CONVD  2176
#define LSEQ   2048
#define ROWS   8192
#define NCHUNK 32

static __device__ __forceinline__ float bf2f(u16 u) {
  u32 x = ((u32)u) << 16;
  return __builtin_bit_cast(float, x);
}
static __device__ __forceinline__ u16 f2bf(float f) {
  u32 x = __builtin_bit_cast(u32, f);
  x += 0x7fffu + ((x >> 16) & 1u);
  return (u16)(x >> 16);
}
static __device__ __forceinline__ f32x4 mfma16(short8 a, short8 b, f32x4 c) {
  return __builtin_amdgcn_mfma_f32_16x16x32_bf16(a, b, c, 0, 0, 0);
}

#define GLDS(gp, lp)                                                     \
  __builtin_amdgcn_global_load_lds(                                     \
      (const __attribute__((address_space(1))) void*)(gp),              \
      (__attribute__((address_space(3))) void*)(lp), 16, 0, 0)

// ---------------- f32 -> bf16 weight cast ----------------
__global__ __launch_bounds__(256) void k_cast(const float* __restrict__ s, u16* __restrict__ d) {
  size_t i = ((size_t)blockIdx.x * 256 + threadIdx.x) * 4;
  float4 v = *(const float4*)(s + i);
  u32 lo = (u32)f2bf(v.x) | ((u32)f2bf(v.y) << 16);
  u32 hi = (u32)f2bf(v.z) | ((u32)f2bf(v.w) << 16);
  *(uint2*)(d + i) = make_uint2(lo, hi);
}

// ---------------- res = h + r ; hnorm = rmsnorm(res)*w (bf16) ----------------
__global__ __launch_bounds__(256) void k_addnorm(const float* __restrict__ h,
                                                 const float* __restrict__ r,
                                                 const float* __restrict__ nw,
                                                 float* __restrict__ res,
                                                 u16* __restrict__ hn) {
  int row = blockIdx.x, t = threadIdx.x;
  const float4* hp = (const float4*)(h + (size_t)row * DMODEL);
  const float4* rp = (const float4*)(r + (size_t)row * DMODEL);
  float4 a = hp[t], b = rp[t];
  float4 s;
  s.x = a.x + b.x; s.y = a.y + b.y; s.z = a.z + b.z; s.w = a.w + b.w;
  ((float4*)(res + (size_t)row * DMODEL))[t] = s;
  float ss = s.x * s.x + s.y * s.y + s.z * s.z + s.w * s.w;
  for (int m = 32; m; m >>= 1) ss += __shfl_xor(ss, m);
  __shared__ float wsum[4];
  if ((t & 63) == 0) wsum[t >> 6] = ss;
  __syncthreads();
  float tot = wsum[0] + wsum[1] + wsum[2] + wsum[3];
  float rinv = rsqrtf(tot * (1.0f / DMODEL) + 1e-5f);
  float4 w4 = ((const float4*)nw)[t];
  u32 lo = (u32)f2bf(s.x * rinv * w4.x) | ((u32)f2bf(s.y * rinv * w4.y) << 16);
  u32 hi = (u32)f2bf(s.z * rinv * w4.z) | ((u32)f2bf(s.w * rinv * w4.w) << 16);
  *(uint2*)(hn + (size_t)row * DMODEL + t * 4) = make_uint2(lo, hi);
}

// ---------------- bf16 MFMA GEMM: 128x256 tile, 8 waves, BK=64, 2-phase 1-barrier ----------------
// ROUND-8 CONFIG (proven fastest: in_proj 190 us). Single-barrier loop:
//   STAGE(t+1) -> ds_read buf[t] + MFMA -> vmcnt(0) -> barrier.
// A-panel-linear XCD remap: wg = (orig&7)*cpx + orig>>3; brow = wg/nN.
// (Round 9/10 established: dual-barrier and supertile remap both REGRESS.)
template <int MODE>
__global__ __launch_bounds__(512) void k_gemm(const u16* __restrict__ A,
                                              const u16* __restrict__ Bw, int K, int nN,
                                              float* __restrict__ outf,
                                              u16* __restrict__ zb, u16* __restrict__ xb,
                                              float* __restrict__ dtp,
                                              const float* __restrict__ dt_bias) {
  constexpr int ABY = 128 * 64 * 2;   // 16 KB A tile
  constexpr int BBY = 256 * 64 * 2;   // 32 KB B tile
  constexpr int TB = ABY + BBY;       // 48 KB per buffer
  __shared__ char lds[2 * TB];

  const int tid = threadIdx.x, wave = tid >> 6, lane = tid & 63;
  const int wm = wave >> 2, wn = wave & 3;
  const int lr = lane & 15, lg = lane >> 4;

  const int cpx = gridDim.x >> 3;
  const int orig = blockIdx.x;
  const int wg = (orig & 7) * cpx + (orig >> 3);
  const int brow = (wg / nN) * 128;
  const int bcol = (wg % nN) * 256;
  const int NK = K >> 6;

  size_t srcA[2], srcB[4];
#pragma unroll
  for (int g = 0; g < 2; ++g) {
    int d = g * 8192 + tid * 16;
    int s = d ^ (((d >> 7) & 7) << 4);
    srcA[g] = (size_t)(brow + (s >> 7)) * K + ((s & 127) >> 1);
  }
#pragma unroll
  for (int g = 0; g < 4; ++g) {
    int d = g * 8192 + tid * 16;
    int s = d ^ (((d >> 7) & 7) << 4);
    srcB[g] = (size_t)(bcol + (s >> 7)) * K + ((s & 127) >> 1);
  }

  auto STAGE = [&](int buf, int kt) {
    char* base = lds + buf * TB;
    size_t koff = (size_t)kt * 64;
#pragma unroll
    for (int g = 0; g < 2; ++g)
      GLDS(A + srcA[g] + koff, base + g * 8192 + wave * 1024);
#pragma unroll
    for (int g = 0; g < 4; ++g)
      GLDS(Bw + srcB[g] + koff, base + ABY + g * 8192 + wave * 1024);
  };

  int offA[4][2], offB[4][2];
#pragma unroll
  for (int i = 0; i < 4; ++i)
#pragma unroll
    for (int ks = 0; ks < 2; ++ks) {
      int rA = wm * 64 + i * 16 + lr;
      offA[i][ks] = (rA * 128 + ks * 64 + lg * 16) ^ ((lr & 7) << 4);
      int rB = wn * 64 + i * 16 + lr;
      offB[i][ks] = ABY + ((rB * 128 + ks * 64 + lg * 16) ^ ((lr & 7) << 4));
    }

  f32x4 acc[4][4] = {};
  STAGE(0, 0);
  asm volatile("s_waitcnt vmcnt(0)" ::: "memory");
  __builtin_amdgcn_s_barrier();
  for (int t = 0; t < NK; ++t) {
    const int cur = t & 1;
    if (t + 1 < NK) STAGE(cur ^ 1, t + 1);
    const char* bb = lds + cur * TB;
    short8 af[4], bfr[4];
#pragma unroll
    for (int i = 0; i < 4; ++i) af[i] = *(const short8*)(bb + offA[i][0]);
#pragma unroll
    for (int j = 0; j < 4; ++j) bfr[j] = *(const short8*)(bb + offB[j][0]);
    __builtin_amdgcn_s_setprio(1);
#pragma unroll
    for (int i = 0; i < 4; ++i)
#pragma unroll
      for (int j = 0; j < 4; ++j) acc[i][j] = mfma16(af[i], bfr[j], acc[i][j]);
    __builtin_amdgcn_s_setprio(0);
#pragma unroll
    for (int i = 0; i < 4; ++i) af[i] = *(const short8*)(bb + offA[i][1]);
#pragma unroll
    for (int j = 0; j < 4; ++j) bfr[j] = *(const short8*)(bb + offB[j][1]);
    __builtin_amdgcn_s_setprio(1);
#pragma unroll
    for (int i = 0; i < 4; ++i)
#pragma unroll
      for (int j = 0; j < 4; ++j) acc[i][j] = mfma16(af[i], bfr[j], acc[i][j]);
    __builtin_amdgcn_s_setprio(0);
    if (t + 1 < NK) {
      asm volatile("s_waitcnt vmcnt(0)" ::: "memory");
      __builtin_amdgcn_s_barrier();
    }
  }

  const int mb = brow + wm * 64 + lg * 4;
  const int nb = bcol + wn * 64 + lr;
#pragma unroll
  for (int i = 0; i < 4; ++i)
#pragma unroll
    for (int j = 0; j < 4; ++j)
#pragma unroll
      for (int rr = 0; rr < 4; ++rr) {
        int m = mb + i * 16 + rr;
        int n = nb + j * 16;
        float v = acc[i][j][rr];
        if constexpr (MODE == 1) {
          outf[(size_t)m * 1024 + n] = v;
        } else {
          if (n < DINNER) {
            zb[(size_t)m * DINNER + n] = f2bf(v);
          } else if (n < DINNER + CONVD) {
            xb[(size_t)m * CONVD + (n - DINNER)] = f2bf(v);
          } else if (n < DIP) {
            int h2 = n - (DINNER + CONVD);  // 0..63
            float uu = v + dt_bias[h2 & 31];
            float sp = (uu > 20.f) ? uu : log1pf(expf(uu));
            int bb2 = m >> 11, tt = m & 2047;
            int obb = bb2, ot = tt;
            if (h2 >= 32) { obb = bb2 + 4; ot = 2047 - tt; }
            dtp[((size_t)(obb << 11) + ot) * NH + (h2 & 31)] = sp;
          }
        }
      }
}

// ---------------- depthwise causal conv (k=4) + SiLU, 8 chans x 4 t-steps/thread ----------------
// 4-t blocking: 7 tap-row loads (112 B) produce 4 outputs (64 B) -> 1.75x read amp
// (was 4x). Reads ~62 MB + writes 36 MB ~= HBM floor.
__global__ __launch_bounds__(256) void k_conv(const u16* __restrict__ xbc,
                                              const float* __restrict__ cw,
                                              const float* __restrict__ cb,
                                              u16* __restrict__ xc, u16* __restrict__ bm,
                                              u16* __restrict__ cm) {
  int e = blockIdx.x * 256 + threadIdx.x;  // e < (ROWS/4)*272 = 557056
  int c8 = e % 272;
  int rq = e / 272;          // (b, t-group)
  int b = rq >> 9;           // rq / 512
  int t0 = (rq & 511) * 4;   // first of 4 t values
  int c = c8 * 8;

  float4 w[8];
  float a[4][8];
#pragma unroll
  for (int j = 0; j < 8; ++j) {
    w[j] = *(const float4*)&cw[(c + j) * 4];
    float bias = cb[c + j];
#pragma unroll
    for (int i = 0; i < 4; ++i) a[i][j] = bias;
  }
  const u16* base = xbc + (size_t)(b << 11) * CONVD + c;
#pragma unroll
  for (int k = 0; k < 7; ++k) {
    int tt = t0 - 3 + k;
    if (tt >= 0) {
      ushort8 v = *(const ushort8*)(base + (size_t)tt * CONVD);
#pragma unroll
      for (int i = 0; i < 4; ++i) {
        int kk = k - i;  // tap index for output i
        if (kk >= 0 && kk < 4) {
#pragma unroll
          for (int j = 0; j < 8; ++j) a[i][j] += bf2f(v[j]) * ((const float*)&w[j])[kk];
        }
      }
    }
  }
#pragma unroll
  for (int i = 0; i < 4; ++i) {
    ushort8 o;
#pragma unroll
    for (int j = 0; j < 8; ++j) {
      float s = a[i][j] * (1.f / (1.f + expf(-a[i][j])));
      o[j] = f2bf(s);
    }
    size_t r = (size_t)(b << 11) + t0 + i;
    if (c8 < 256) *(ushort8*)(xc + r * DINNER + c) = o;
    else if (c8 < 264) *(ushort8*)(bm + r * 64 + (c - DINNER)) = o;
    else *(ushort8*)(cm + r * 64 + (c - DINNER - 64)) = o;
  }
}

// ---------------- fused SSD scan v2: 8 waves, one block per (dir, batch, head) ----------------
__global__ __launch_bounds__(512) void k_ssd(const u16* __restrict__ xc,
                                             const u16* __restrict__ bmat,
                                             const u16* __restrict__ cmat,
                                             const float* __restrict__ dtp,
                                             const float* __restrict__ alog,
                                             u16* __restrict__ y0, u16* __restrict__ y1) {
  const int h = blockIdx.x & 31;
  const int grp = blockIdx.x >> 5;  // 0..7
  const int dir = grp >> 2;
  const int bt = grp & 3;
  const int tid = threadIdx.x, wave = tid >> 6, lane = tid & 63;
  const int lq = wave >> 1, wh = wave & 1;
  const int lr = lane & 15, lg = lane >> 4;
  const float Ah = -expf(alog[h]);

  __shared__ u16 sB[64][72];    // [s][n]
  __shared__ u16 sC[64][72];    // [s][n]
  __shared__ u16 sXM[64][72];   // staged X [s][p]; reused as M [l][s] after transpose
  __shared__ u16 sXT[64][72];   // X^T [p][s]
  __shared__ u16 sBT[64][72];   // B^T [n][s]
  __shared__ u16 sSb[64][72];   // bf16 shadow of state [p][n]
  __shared__ float sS[64][68];  // f32 state accumulator [p][n]
  __shared__ float sAc[64], sEA[64], sSc[64], sDt[64];

  for (int i = tid; i < 64 * 64; i += 512) {
    sS[i >> 6][i & 63] = 0.f;
    sSb[i >> 6][i & 63] = 0;
  }

  const int srow = tid >> 3, q8 = (tid & 7) * 8;

  auto rowOf = [&](int c) {
    int tdir = c * 64 + srow;
    return bt * LSEQ + (dir ? (LSEQ - 1 - tdir) : tdir);
  };

  int rg = rowOf(0);
  ushort8 rB = *(const ushort8*)(bmat + (size_t)rg * 64 + q8);
  ushort8 rC = *(const ushort8*)(cmat + (size_t)rg * 64 + q8);
  ushort8 rX = *(const ushort8*)(xc + (size_t)rg * DINNER + h * 64 + q8);

  for (int c = 0; c < NCHUNK; ++c) {
    // ---- stage (regs -> LDS) ----
    *(ushort8*)&sB[srow][q8] = rB;
    *(ushort8*)&sC[srow][q8] = rC;
    *(ushort8*)&sXM[srow][q8] = rX;
    __syncthreads();  // bar1

    // ---- transpose X, B (wave reads rows w*8..w*8+7, lane = column) + dt scan ----
    {
      ushort8 vx, vb;
#pragma unroll
      for (int i = 0; i < 8; ++i) {
        vx[i] = sXM[wave * 8 + i][lane];
        vb[i] = sB[wave * 8 + i][lane];
      }
      *(ushort8*)&sXT[lane][wave * 8] = vx;
      *(ushort8*)&sBT[lane][wave * 8] = vb;
    }
    if (wave == 0) {
      int s = lane;
      float dv = dtp[((size_t)grp * LSEQ + c * 64 + s) * NH + h];
      float a = dv * Ah;
      float x = a;
#pragma unroll
      for (int d = 1; d < 64; d <<= 1) {
        float y = __shfl_up(x, d);
        if (s >= d) x += y;
      }
      float tot = __shfl(x, 63);
      sAc[s] = x;
      sEA[s] = expf(x);
      sSc[s] = expf(tot - x) * dv;
      sDt[s] = dv;
    }
    __syncthreads();  // bar2

    // ---- early-issue next chunk's global loads (land during PA/PB) ----
    if (c + 1 < NCHUNK) {
      int rg2 = rowOf(c + 1);
      rB = *(const ushort8*)(bmat + (size_t)rg2 * 64 + q8);
      rC = *(const ushort8*)(cmat + (size_t)rg2 * 64 + q8);
      rX = *(const ushort8*)(xc + (size_t)rg2 * DINNER + h * 64 + q8);
    }

    // ---- PA: G = C@B^T -> M (into sXM); Yoff = C @ sSb^T ----
    f32x4 acc_y[2] = {};
    {
      f32x4 acc_g[2] = {};
#pragma unroll
      for (int ks = 0; ks < 2; ++ks) {
        int kof = ks * 32 + lg * 8;
        short8 af = *(const short8*)&sC[lq * 16 + lr][kof];
#pragma unroll
        for (int nt = 0; nt < 2; ++nt) {
          short8 bf = *(const short8*)&sB[wh * 32 + nt * 16 + lr][kof];
          acc_g[nt] = mfma16(af, bf, acc_g[nt]);
        }
      }
#pragma unroll
      for (int ks = 0; ks < 2; ++ks) {
        int kof = ks * 32 + lg * 8;
        short8 af = *(const short8*)&sC[lq * 16 + lr][kof];
#pragma unroll
        for (int nt = 0; nt < 2; ++nt) {
          short8 bf = *(const short8*)&sSb[wh * 32 + nt * 16 + lr][kof];
          acc_y[nt] = mfma16(af, bf, acc_y[nt]);
        }
      }
#pragma unroll
      for (int nt = 0; nt < 2; ++nt)
#pragma unroll
        for (int rr = 0; rr < 4; ++rr) {
          int l = lq * 16 + lg * 4 + rr;
          int s = wh * 32 + nt * 16 + lr;
          float g = acc_g[nt][rr];
          float m = (l >= s) ? g * sDt[s] * expf(sAc[l] - sAc[s]) : 0.f;
          sXM[l][s] = f2bf(m);
        }
    }
    __syncthreads();  // bar3

    // ---- PB: Y = Yoff*exp(Ac) + M@X^T; store; S update ----
#pragma unroll
    for (int nt = 0; nt < 2; ++nt)
#pragma unroll
      for (int rr = 0; rr < 4; ++rr) acc_y[nt][rr] *= sEA[lq * 16 + lg * 4 + rr];
#pragma unroll
    for (int ks = 0; ks < 2; ++ks) {
      int kof = ks * 32 + lg * 8;
      short8 af = *(const short8*)&sXM[lq * 16 + lr][kof];
#pragma unroll
      for (int nt = 0; nt < 2; ++nt) {
        short8 bf = *(const short8*)&sXT[wh * 32 + nt * 16 + lr][kof];
        acc_y[nt] = mfma16(af, bf, acc_y[nt]);
      }
    }
#pragma unroll
    for (int nt = 0; nt < 2; ++nt)
#pragma unroll
      for (int rr = 0; rr < 4; ++rr) {
        int l = lq * 16 + lg * 4 + rr;
        int p = wh * 32 + nt * 16 + lr;
        int tg = c * 64 + l;
        if (tg <= LSEQ - 2) {
          float v = acc_y[nt][rr];
          if (dir == 0)
            y0[((size_t)bt * LSEQ + tg + 1) * DINNER + h * 64 + p] = f2bf(v);
          else
            y1[((size_t)bt * LSEQ + (LSEQ - 2 - tg)) * DINNER + h * 64 + p] = f2bf(v);
        }
      }
    if (c == 0 && tid < 64) {
      if (dir == 0)
        y0[((size_t)bt * LSEQ) * DINNER + h * 64 + tid] = 0;
      else
        y1[((size_t)bt * LSEQ + (LSEQ - 1)) * DINNER + h * 64 + tid] = 0;
    }
    // chunk state: S = lam*S + (X*w)^T @ B
    {
      f32x4 acc_s[2] = {};
#pragma unroll
      for (int ks = 0; ks < 2; ++ks) {
        int kof = ks * 32 + lg * 8;
        ushort8 xr = *(const ushort8*)&sXT[lq * 16 + lr][kof];
        short8 af;
#pragma unroll
        for (int e = 0; e < 8; ++e) af[e] = (short)f2bf(bf2f(xr[e]) * sSc[kof + e]);
#pragma unroll
        for (int nt = 0; nt < 2; ++nt) {
          short8 bf = *(const short8*)&sBT[wh * 32 + nt * 16 + lr][kof];
          acc_s[nt] = mfma16(af, bf, acc_s[nt]);
        }
      }
      float lam = sEA[63];
#pragma unroll
      for (int nt = 0; nt < 2; ++nt)
#pragma unroll
        for (int rr = 0; rr < 4; ++rr) {
          int p = lq * 16 + lg * 4 + rr;
          int n = wh * 32 + nt * 16 + lr;
          float ns = lam * sS[p][n] + acc_s[nt][rr];
          sS[p][n] = ns;
          sSb[p][n] = f2bf(ns);
        }
    }
    __syncthreads();  // bar4
  }
}

// ---------------- Deff = x @ fc_D_w^T + D  (MFMA, split-K, 32 rows/block) ----------------
__global__ __launch_bounds__(256) void k_deff(const u16* __restrict__ xcv,
                                              const u16* __restrict__ fwb,
                                              const float* __restrict__ Dv,
                                              float* __restrict__ deff) {
  __shared__ float red[2][64][8];
  const int tid = threadIdx.x, wave = tid >> 6, lane = tid & 63;
  const int lr = lane & 15, lg = lane >> 4;
  const int rowg = wave & 1;
  const int kg = wave >> 1;
  const int rb = blockIdx.x * 32 + rowg * 16;
  const u16* xrow = xcv + (size_t)(rb + lr) * DINNER + kg * 1024 + lg * 8;
  const u16* f0 = fwb + (size_t)lr * DINNER + kg * 1024 + lg * 8;
  const u16* f1 = fwb + (size_t)(16 + lr) * DINNER + kg * 1024 + lg * 8;
  f32x4 a0 = {}, a1 = {};
  for (int k = 0; k < 1024; k += 32) {
    short8 bf = *(const short8*)(xrow + k);
    short8 af0 = *(const short8*)(f0 + k);
    short8 af1 = *(const short8*)(f1 + k);
    a0 = mfma16(af0, bf, a0);
    a1 = mfma16(af1, bf, a1);
  }
  if (kg == 1) {
#pragma unroll
    for (int rr = 0; rr < 4; ++rr) {
      red[rowg][lane][rr] = a0[rr];
      red[rowg][lane][4 + rr] = a1[rr];
    }
  }
  __syncthreads();
  if (kg == 0) {
    float4 o0, o1;
#pragma unroll
    for (int rr = 0; rr < 4; ++rr) {
      ((float*)&o0)[rr] = a0[rr] + red[rowg][lane][rr] + Dv[lg * 4 + rr];
      ((float*)&o1)[rr] = a1[rr] + red[rowg][lane][4 + rr] + Dv[16 + lg * 4 + rr];
    }
    *(float4*)&deff[(size_t)(rb + lr) * NH + lg * 4] = o0;
    *(float4*)&deff[(size_t)(rb + lr) * NH + 16 + lg * 4] = o1;
  }
}

// ---------------- gating: yn = rmsnorm((y0 + y1 + x*Deff) * silu(z)) * gnw ----------------
__global__ __launch_bounds__(256) void k_gate(const u16* __restrict__ yb0,
                                              const u16* __restrict__ yb1,
                                              const u16* __restrict__ xcv,
                                              const float* __restrict__ deff,
                                              const u16* __restrict__ zb,
                                              const float* __restrict__ gnw,
                                              u16* __restrict__ yn) {
  int row = blockIdx.x, t = threadIdx.x;
  size_t base = (size_t)row * DINNER + t * 8;
  ushort8 y0v = *(const ushort8*)(yb0 + base);
  ushort8 y1v = *(const ushort8*)(yb1 + base);
  ushort8 xv = *(const ushort8*)(xcv + base);
  ushort8 zv = *(const ushort8*)(zb + base);
  float de = deff[row * NH + (t >> 3)];
  float g[8];
  float ss = 0.f;
#pragma unroll
  for (int j = 0; j < 8; ++j) {
    float y = bf2f(y0v[j]) + bf2f(y1v[j]) + bf2f(xv[j]) * de;
    float z = bf2f(zv[j]);
    float gg = y * (z / (1.f + expf(-z)));
    g[j] = gg;
    ss += gg * gg;
  }
  for (int m = 32; m; m >>= 1) ss += __shfl_xor(ss, m);
  __shared__ float wsum[4];
  if ((t & 63) == 0) wsum[t >> 6] = ss;
  __syncthreads();
  float tot = wsum[0] + wsum[1] + wsum[2] + wsum[3];
  float rinv = rsqrtf(tot * (1.0f / DINNER) + 1e-5f);
  u32 w0 = (u32)f2bf(g[0] * rinv * gnw[t * 8 + 0]) | ((u32)f2bf(g[1] * rinv * gnw[t * 8 + 1]) << 16);
  u32 w1 = (u32)f2bf(g[2] * rinv * gnw[t * 8 + 2]) | ((u32)f2bf(g[3] * rinv * gnw[t * 8 + 3]) << 16);
  u32 w2 = (u32)f2bf(g[4] * rinv * gnw[t * 8 + 4]) | ((u32)f2bf(g[5] * rinv * gnw[t * 8 + 5]) << 16);
  u32 w3 = (u32)f2bf(g[6] * rinv * gnw[t * 8 + 6]) | ((u32)f2bf(g[7] * rinv * gnw[t * 8 + 7]) << 16);
  *(uint4*)(yn + base) = make_uint4(w0, w1, w2, w3);
}

extern "C" void kernel_launch(void* const* d_in, const int* in_sizes, int n_in,
                              void* d_out, int out_size, void* d_ws, size_t ws_size,
                              hipStream_t stream) {
  (void)in_sizes; (void)n_in; (void)out_size; (void)ws_size;
  const float* hid = (const float*)d_in[0];
  const float* resin = (const float*)d_in[1];
  const float* nw = (const float*)d_in[2];
  const float* w1 = (const float*)d_in[3];
  const float* cw = (const float*)d_in[4];
  const float* cb = (const float*)d_in[5];
  const float* dtb = (const float*)d_in[6];
  const float* alog = (const float*)d_in[7];
  const float* Dv = (const float*)d_in[8];
  const float* fcw = (const float*)d_in[9];
  const float* gnw = (const float*)d_in[10];
  const float* w2 = (const float*)d_in[11];
  float* out = (float*)d_out;
  float* resout = out + (size_t)ROWS * DMODEL;

  char* ws = (char*)d_ws;
  size_t o = 0;
  auto alloc = [&](size_t bytes) {
    char* p = ws + o;
    o += (bytes + 255) & ~(size_t)255;
    return p;
  };
  u16* W1b = (u16*)alloc((size_t)DIP_PAD * DMODEL * 2);  // 8.9 MB (reused for W2b)
  u16* HN = (u16*)alloc((size_t)ROWS * DMODEL * 2);      // 16.8 MB (reused for YN)
  u16* XBC = (u16*)alloc((size_t)ROWS * CONVD * 2);      // 35.7 MB (reused for YB0)
  u16* ZB = (u16*)alloc((size_t)ROWS * DINNER * 2);      // 33.6 MB
  u16* XC = (u16*)alloc((size_t)ROWS * DINNER * 2);      // 33.6 MB
  u16* BM = (u16*)alloc((size_t)ROWS * 64 * 2);          // 1 MB
  u16* CM = (u16*)alloc((size_t)ROWS * 64 * 2);          // 1 MB
  float* DT = (float*)alloc((size_t)8 * LSEQ * NH * 4);  // 2 MB
  float* DE = (float*)alloc((size_t)ROWS * NH * 4);      // 1 MB
  u16* FWB = (u16*)alloc((size_t)NH * DINNER * 2);       // 128 KB
  u16* YB0 = XBC;
  u16* YB1 = (u16*)out;  // out region (33.55 MB) is dead until final GEMM
  u16* W2b = W1b;
  u16* YN = HN;

  k_cast<<<(DIP * DMODEL) / 1024, 256, 0, stream>>>(w1, W1b);
  k_addnorm<<<ROWS, 256, 0, stream>>>(hid, resin, nw, resout, HN);
  // in_proj: M=8192 (64 tiles of 128), N=4352 (17 tiles of 256), K=1024
  k_gemm<0><<<64 * 17, 512, 0, stream>>>(HN, W1b, DMODEL, 17, nullptr, ZB, XBC, DT, dtb);
  k_conv<<<(ROWS / 4) * 272 / 256, 256, 0, stream>>>(XBC, cw, cb, XC, BM, CM);
  k_ssd<<<256, 512, 0, stream>>>(XC, BM, CM, DT, alog, YB0, YB1);
  k_cast<<<(DMODEL * DINNER) / 1024, 256, 0, stream>>>(w2, W2b);
  k_cast<<<(NH * DINNER) / 1024, 256, 0, stream>>>(fcw, FWB);
  k_deff<<<ROWS / 32, 256, 0, stream>>>(XC, FWB, Dv, DE);
  k_gate<<<ROWS, 256, 0, stream>>>(YB0, YB1, XC, DE, ZB, gnw, YN);
  // out_proj: M=8192 (64 tiles), N=1024 (4 tiles of 256), K=2048
  k_gemm<1><<<64 * 4, 512, 0, stream>>>(YN, W2b, DINNER, 4, out, nullptr, nullptr, nullptr,
                                        nullptr);
}

// Round 12
// 407.083 us; speedup vs baseline: 1.2446x; 1.0003x over previous
//
#include <hip/hip_runtime.h>

typedef __attribute__((ext_vector_type(4))) float f32x4;
typedef __attribute__((ext_vector_type(8))) short short8;
typedef __attribute__((ext_vector_type(8))) unsigned short ushort8;
typedef unsigned short u16;
typedef unsigned int u32;

#define DMODEL 1024
#define DINNER 2048
#define NH     32
#define DIP    4288
#define DIP_PAD 4352
#define CONVD  2176
#define LSEQ   2048
#define ROWS   8192
#define NCHUNK 32

static __device__ __forceinline__ float bf2f(u16 u) {
  u32 x = ((u32)u) << 16;
  return __builtin_bit_cast(float, x);
}
static __device__ __forceinline__ u16 f2bf(float f) {
  u32 x = __builtin_bit_cast(u32, f);
  x += 0x7fffu + ((x >> 16) & 1u);
  return (u16)(x >> 16);
}
static __device__ __forceinline__ f32x4 mfma16(short8 a, short8 b, f32x4 c) {
  return __builtin_amdgcn_mfma_f32_16x16x32_bf16(a, b, c, 0, 0, 0);
}

#define GLDS(gp, lp)                                                     \
  __builtin_amdgcn_global_load_lds(                                     \
      (const __attribute__((address_space(1))) void*)(gp),              \
      (__attribute__((address_space(3))) void*)(lp), 16, 0, 0)

// ---------------- f32 -> bf16 weight cast ----------------
__global__ __launch_bounds__(256) void k_cast(const float* __restrict__ s, u16* __restrict__ d) {
  size_t i = ((size_t)blockIdx.x * 256 + threadIdx.x) * 4;
  float4 v = *(const float4*)(s + i);
  u32 lo = (u32)f2bf(v.x) | ((u32)f2bf(v.y) << 16);
  u32 hi = (u32)f2bf(v.z) | ((u32)f2bf(v.w) << 16);
  *(uint2*)(d + i) = make_uint2(lo, hi);
}

// ---------------- res = h + r ; hnorm = rmsnorm(res)*w (bf16) ----------------
__global__ __launch_bounds__(256) void k_addnorm(const float* __restrict__ h,
                                                 const float* __restrict__ r,
                                                 const float* __restrict__ nw,
                                                 float* __restrict__ res,
                                                 u16* __restrict__ hn) {
  int row = blockIdx.x, t = threadIdx.x;
  const float4* hp = (const float4*)(h + (size_t)row * DMODEL);
  const float4* rp = (const float4*)(r + (size_t)row * DMODEL);
  float4 a = hp[t], b = rp[t];
  float4 s;
  s.x = a.x + b.x; s.y = a.y + b.y; s.z = a.z + b.z; s.w = a.w + b.w;
  ((float4*)(res + (size_t)row * DMODEL))[t] = s;
  float ss = s.x * s.x + s.y * s.y + s.z * s.z + s.w * s.w;
  for (int m = 32; m; m >>= 1) ss += __shfl_xor(ss, m);
  __shared__ float wsum[4];
  if ((t & 63) == 0) wsum[t >> 6] = ss;
  __syncthreads();
  float tot = wsum[0] + wsum[1] + wsum[2] + wsum[3];
  float rinv = rsqrtf(tot * (1.0f / DMODEL) + 1e-5f);
  float4 w4 = ((const float4*)nw)[t];
  u32 lo = (u32)f2bf(s.x * rinv * w4.x) | ((u32)f2bf(s.y * rinv * w4.y) << 16);
  u32 hi = (u32)f2bf(s.z * rinv * w4.z) | ((u32)f2bf(s.w * rinv * w4.w) << 16);
  *(uint2*)(hn + (size_t)row * DMODEL + t * 4) = make_uint2(lo, hi);
}

// ---------------- bf16 MFMA GEMM: 128x256 tile, 8 waves, BK=64 ----------------
// Round-8 single-barrier loop + DEPTH-2 counted vmcnt (this round's one change):
// triple-buffered LDS (3 x 48 KB); STAGE(t+2) at top; loop-end wait is vmcnt(6)
// (tile t+1 landed, t+2 stays in flight across the barrier). Loads get ~2 full
// iterations to land instead of one. STAGE(t+2) overwrites buf[(t-1)%3], whose
// readers all passed the end-of-iter-(t-1) barrier.
template <int MODE>
__global__ __launch_bounds__(512) void k_gemm(const u16* __restrict__ A,
                                              const u16* __restrict__ Bw, int K, int nN,
                                              float* __restrict__ outf,
                                              u16* __restrict__ zb, u16* __restrict__ xb,
                                              float* __restrict__ dtp,
                                              const float* __restrict__ dt_bias) {
  constexpr int ABY = 128 * 64 * 2;   // 16 KB A tile
  constexpr int BBY = 256 * 64 * 2;   // 32 KB B tile
  constexpr int TB = ABY + BBY;       // 48 KB per buffer
  __shared__ char lds[3 * TB];        // 144 KB

  const int tid = threadIdx.x, wave = tid >> 6, lane = tid & 63;
  const int wm = wave >> 2, wn = wave & 3;
  const int lr = lane & 15, lg = lane >> 4;

  const int cpx = gridDim.x >> 3;
  const int orig = blockIdx.x;
  const int wg = (orig & 7) * cpx + (orig >> 3);
  const int brow = (wg / nN) * 128;
  const int bcol = (wg % nN) * 256;
  const int NK = K >> 6;

  size_t srcA[2], srcB[4];
#pragma unroll
  for (int g = 0; g < 2; ++g) {
    int d = g * 8192 + tid * 16;
    int s = d ^ (((d >> 7) & 7) << 4);
    srcA[g] = (size_t)(brow + (s >> 7)) * K + ((s & 127) >> 1);
  }
#pragma unroll
  for (int g = 0; g < 4; ++g) {
    int d = g * 8192 + tid * 16;
    int s = d ^ (((d >> 7) & 7) << 4);
    srcB[g] = (size_t)(bcol + (s >> 7)) * K + ((s & 127) >> 1);
  }

  auto STAGE = [&](int buf, int kt) {
    char* base = lds + buf * TB;
    size_t koff = (size_t)kt * 64;
#pragma unroll
    for (int g = 0; g < 2; ++g)
      GLDS(A + srcA[g] + koff, base + g * 8192 + wave * 1024);
#pragma unroll
    for (int g = 0; g < 4; ++g)
      GLDS(Bw + srcB[g] + koff, base + ABY + g * 8192 + wave * 1024);
  };

  int offA[4][2], offB[4][2];
#pragma unroll
  for (int i = 0; i < 4; ++i)
#pragma unroll
    for (int ks = 0; ks < 2; ++ks) {
      int rA = wm * 64 + i * 16 + lr;
      offA[i][ks] = (rA * 128 + ks * 64 + lg * 16) ^ ((lr & 7) << 4);
      int rB = wn * 64 + i * 16 + lr;
      offB[i][ks] = ABY + ((rB * 128 + ks * 64 + lg * 16) ^ ((lr & 7) << 4));
    }

  f32x4 acc[4][4] = {};
  STAGE(0, 0);
  STAGE(1, 1);
  asm volatile("s_waitcnt vmcnt(6)" ::: "memory");  // tile 0 landed; tile 1 in flight
  __builtin_amdgcn_s_barrier();
  int cur = 0;
  for (int t = 0; t < NK; ++t) {
    if (t + 2 < NK) {
      int nb3 = cur + 2;
      if (nb3 >= 3) nb3 -= 3;
      STAGE(nb3, t + 2);
    }
    const char* bb = lds + cur * TB;
    short8 af[4], bfr[4];
#pragma unroll
    for (int i = 0; i < 4; ++i) af[i] = *(const short8*)(bb + offA[i][0]);
#pragma unroll
    for (int j = 0; j < 4; ++j) bfr[j] = *(const short8*)(bb + offB[j][0]);
    __builtin_amdgcn_s_setprio(1);
#pragma unroll
    for (int i = 0; i < 4; ++i)
#pragma unroll
      for (int j = 0; j < 4; ++j) acc[i][j] = mfma16(af[i], bfr[j], acc[i][j]);
    __builtin_amdgcn_s_setprio(0);
#pragma unroll
    for (int i = 0; i < 4; ++i) af[i] = *(const short8*)(bb + offA[i][1]);
#pragma unroll
    for (int j = 0; j < 4; ++j) bfr[j] = *(const short8*)(bb + offB[j][1]);
    __builtin_amdgcn_s_setprio(1);
#pragma unroll
    for (int i = 0; i < 4; ++i)
#pragma unroll
      for (int j = 0; j < 4; ++j) acc[i][j] = mfma16(af[i], bfr[j], acc[i][j]);
    __builtin_amdgcn_s_setprio(0);
    if (t + 1 < NK) {
      if (t + 2 < NK)
        asm volatile("s_waitcnt vmcnt(6)" ::: "memory");  // t+1 landed; t+2 in flight
      else
        asm volatile("s_waitcnt vmcnt(0)" ::: "memory");
      __builtin_amdgcn_s_barrier();
    }
    cur = cur + 1;
    if (cur >= 3) cur = 0;
  }

  const int mb = brow + wm * 64 + lg * 4;
  const int nb = bcol + wn * 64 + lr;
#pragma unroll
  for (int i = 0; i < 4; ++i)
#pragma unroll
    for (int j = 0; j < 4; ++j)
#pragma unroll
      for (int rr = 0; rr < 4; ++rr) {
        int m = mb + i * 16 + rr;
        int n = nb + j * 16;
        float v = acc[i][j][rr];
        if constexpr (MODE == 1) {
          outf[(size_t)m * 1024 + n] = v;
        } else {
          if (n < DINNER) {
            zb[(size_t)m * DINNER + n] = f2bf(v);
          } else if (n < DINNER + CONVD) {
            xb[(size_t)m * CONVD + (n - DINNER)] = f2bf(v);
          } else if (n < DIP) {
            int h2 = n - (DINNER + CONVD);  // 0..63
            float uu = v + dt_bias[h2 & 31];
            float sp = (uu > 20.f) ? uu : log1pf(expf(uu));
            int bb2 = m >> 11, tt = m & 2047;
            int obb = bb2, ot = tt;
            if (h2 >= 32) { obb = bb2 + 4; ot = 2047 - tt; }
            dtp[((size_t)(obb << 11) + ot) * NH + (h2 & 31)] = sp;
          }
        }
      }
}

// ---------------- depthwise causal conv (k=4) + SiLU, 8 chans x 4 t-steps/thread ----------------
__global__ __launch_bounds__(256) void k_conv(const u16* __restrict__ xbc,
                                              const float* __restrict__ cw,
                                              const float* __restrict__ cb,
                                              u16* __restrict__ xc, u16* __restrict__ bm,
                                              u16* __restrict__ cm) {
  int e = blockIdx.x * 256 + threadIdx.x;  // e < (ROWS/4)*272 = 557056
  int c8 = e % 272;
  int rq = e / 272;          // (b, t-group)
  int b = rq >> 9;           // rq / 512
  int t0 = (rq & 511) * 4;   // first of 4 t values
  int c = c8 * 8;

  float4 w[8];
  float a[4][8];
#pragma unroll
  for (int j = 0; j < 8; ++j) {
    w[j] = *(const float4*)&cw[(c + j) * 4];
    float bias = cb[c + j];
#pragma unroll
    for (int i = 0; i < 4; ++i) a[i][j] = bias;
  }
  const u16* base = xbc + (size_t)(b << 11) * CONVD + c;
#pragma unroll
  for (int k = 0; k < 7; ++k) {
    int tt = t0 - 3 + k;
    if (tt >= 0) {
      ushort8 v = *(const ushort8*)(base + (size_t)tt * CONVD);
#pragma unroll
      for (int i = 0; i < 4; ++i) {
        int kk = k - i;  // tap index for output i
        if (kk >= 0 && kk < 4) {
#pragma unroll
          for (int j = 0; j < 8; ++j) a[i][j] += bf2f(v[j]) * ((const float*)&w[j])[kk];
        }
      }
    }
  }
#pragma unroll
  for (int i = 0; i < 4; ++i) {
    ushort8 o;
#pragma unroll
    for (int j = 0; j < 8; ++j) {
      float s = a[i][j] * (1.f / (1.f + expf(-a[i][j])));
      o[j] = f2bf(s);
    }
    size_t r = (size_t)(b << 11) + t0 + i;
    if (c8 < 256) *(ushort8*)(xc + r * DINNER + c) = o;
    else if (c8 < 264) *(ushort8*)(bm + r * 64 + (c - DINNER)) = o;
    else *(ushort8*)(cm + r * 64 + (c - DINNER - 64)) = o;
  }
}

// ---------------- fused SSD scan v2: 8 waves, one block per (dir, batch, head) ----------------
__global__ __launch_bounds__(512) void k_ssd(const u16* __restrict__ xc,
                                             const u16* __restrict__ bmat,
                                             const u16* __restrict__ cmat,
                                             const float* __restrict__ dtp,
                                             const float* __restrict__ alog,
                                             u16* __restrict__ y0, u16* __restrict__ y1) {
  const int h = blockIdx.x & 31;
  const int grp = blockIdx.x >> 5;  // 0..7
  const int dir = grp >> 2;
  const int bt = grp & 3;
  const int tid = threadIdx.x, wave = tid >> 6, lane = tid & 63;
  const int lq = wave >> 1, wh = wave & 1;
  const int lr = lane & 15, lg = lane >> 4;
  const float Ah = -expf(alog[h]);

  __shared__ u16 sB[64][72];    // [s][n]
  __shared__ u16 sC[64][72];    // [s][n]
  __shared__ u16 sXM[64][72];   // staged X [s][p]; reused as M [l][s] after transpose
  __shared__ u16 sXT[64][72];   // X^T [p][s]
  __shared__ u16 sBT[64][72];   // B^T [n][s]
  __shared__ u16 sSb[64][72];   // bf16 shadow of state [p][n]
  __shared__ float sS[64][68];  // f32 state accumulator [p][n]
  __shared__ float sAc[64], sEA[64], sSc[64], sDt[64];

  for (int i = tid; i < 64 * 64; i += 512) {
    sS[i >> 6][i & 63] = 0.f;
    sSb[i >> 6][i & 63] = 0;
  }

  const int srow = tid >> 3, q8 = (tid & 7) * 8;

  auto rowOf = [&](int c) {
    int tdir = c * 64 + srow;
    return bt * LSEQ + (dir ? (LSEQ - 1 - tdir) : tdir);
  };

  int rg = rowOf(0);
  ushort8 rB = *(const ushort8*)(bmat + (size_t)rg * 64 + q8);
  ushort8 rC = *(const ushort8*)(cmat + (size_t)rg * 64 + q8);
  ushort8 rX = *(const ushort8*)(xc + (size_t)rg * DINNER + h * 64 + q8);

  for (int c = 0; c < NCHUNK; ++c) {
    // ---- stage (regs -> LDS) ----
    *(ushort8*)&sB[srow][q8] = rB;
    *(ushort8*)&sC[srow][q8] = rC;
    *(ushort8*)&sXM[srow][q8] = rX;
    __syncthreads();  // bar1

    // ---- transpose X, B (wave reads rows w*8..w*8+7, lane = column) + dt scan ----
    {
      ushort8 vx, vb;
#pragma unroll
      for (int i = 0; i < 8; ++i) {
        vx[i] = sXM[wave * 8 + i][lane];
        vb[i] = sB[wave * 8 + i][lane];
      }
      *(ushort8*)&sXT[lane][wave * 8] = vx;
      *(ushort8*)&sBT[lane][wave * 8] = vb;
    }
    if (wave == 0) {
      int s = lane;
      float dv = dtp[((size_t)grp * LSEQ + c * 64 + s) * NH + h];
      float a = dv * Ah;
      float x = a;
#pragma unroll
      for (int d = 1; d < 64; d <<= 1) {
        float y = __shfl_up(x, d);
        if (s >= d) x += y;
      }
      float tot = __shfl(x, 63);
      sAc[s] = x;
      sEA[s] = expf(x);
      sSc[s] = expf(tot - x) * dv;
      sDt[s] = dv;
    }
    __syncthreads();  // bar2

    // ---- early-issue next chunk's global loads (land during PA/PB) ----
    if (c + 1 < NCHUNK) {
      int rg2 = rowOf(c + 1);
      rB = *(const ushort8*)(bmat + (size_t)rg2 * 64 + q8);
      rC = *(const ushort8*)(cmat + (size_t)rg2 * 64 + q8);
      rX = *(const ushort8*)(xc + (size_t)rg2 * DINNER + h * 64 + q8);
    }

    // ---- PA: G = C@B^T -> M (into sXM); Yoff = C @ sSb^T ----
    f32x4 acc_y[2] = {};
    {
      f32x4 acc_g[2] = {};
#pragma unroll
      for (int ks = 0; ks < 2; ++ks) {
        int kof = ks * 32 + lg * 8;
        short8 af = *(const short8*)&sC[lq * 16 + lr][kof];
#pragma unroll
        for (int nt = 0; nt < 2; ++nt) {
          short8 bf = *(const short8*)&sB[wh * 32 + nt * 16 + lr][kof];
          acc_g[nt] = mfma16(af, bf, acc_g[nt]);
        }
      }
#pragma unroll
      for (int ks = 0; ks < 2; ++ks) {
        int kof = ks * 32 + lg * 8;
        short8 af = *(const short8*)&sC[lq * 16 + lr][kof];
#pragma unroll
        for (int nt = 0; nt < 2; ++nt) {
          short8 bf = *(const short8*)&sSb[wh * 32 + nt * 16 + lr][kof];
          acc_y[nt] = mfma16(af, bf, acc_y[nt]);
        }
      }
#pragma unroll
      for (int nt = 0; nt < 2; ++nt)
#pragma unroll
        for (int rr = 0; rr < 4; ++rr) {
          int l = lq * 16 + lg * 4 + rr;
          int s = wh * 32 + nt * 16 + lr;
          float g = acc_g[nt][rr];
          float m = (l >= s) ? g * sDt[s] * expf(sAc[l] - sAc[s]) : 0.f;
          sXM[l][s] = f2bf(m);
        }
    }
    __syncthreads();  // bar3

    // ---- PB: Y = Yoff*exp(Ac) + M@X^T; store; S update ----
#pragma unroll
    for (int nt = 0; nt < 2; ++nt)
#pragma unroll
      for (int rr = 0; rr < 4; ++rr) acc_y[nt][rr] *= sEA[lq * 16 + lg * 4 + rr];
#pragma unroll
    for (int ks = 0; ks < 2; ++ks) {
      int kof = ks * 32 + lg * 8;
      short8 af = *(const short8*)&sXM[lq * 16 + lr][kof];
#pragma unroll
      for (int nt = 0; nt < 2; ++nt) {
        short8 bf = *(const short8*)&sXT[wh * 32 + nt * 16 + lr][kof];
        acc_y[nt] = mfma16(af, bf, acc_y[nt]);
      }
    }
#pragma unroll
    for (int nt = 0; nt < 2; ++nt)
#pragma unroll
      for (int rr = 0; rr < 4; ++rr) {
        int l = lq * 16 + lg * 4 + rr;
        int p = wh * 32 + nt * 16 + lr;
        int tg = c * 64 + l;
        if (tg <= LSEQ - 2) {
          float v = acc_y[nt][rr];
          if (dir == 0)
            y0[((size_t)bt * LSEQ + tg + 1) * DINNER + h * 64 + p] = f2bf(v);
          else
            y1[((size_t)bt * LSEQ + (LSEQ - 2 - tg)) * DINNER + h * 64 + p] = f2bf(v);
        }
      }
    if (c == 0 && tid < 64) {
      if (dir == 0)
        y0[((size_t)bt * LSEQ) * DINNER + h * 64 + tid] = 0;
      else
        y1[((size_t)bt * LSEQ + (LSEQ - 1)) * DINNER + h * 64 + tid] = 0;
    }
    // chunk state: S = lam*S + (X*w)^T @ B
    {
      f32x4 acc_s[2] = {};
#pragma unroll
      for (int ks = 0; ks < 2; ++ks) {
        int kof = ks * 32 + lg * 8;
        ushort8 xr = *(const ushort8*)&sXT[lq * 16 + lr][kof];
        short8 af;
#pragma unroll
        for (int e = 0; e < 8; ++e) af[e] = (short)f2bf(bf2f(xr[e]) * sSc[kof + e]);
#pragma unroll
        for (int nt = 0; nt < 2; ++nt) {
          short8 bf = *(const short8*)&sBT[wh * 32 + nt * 16 + lr][kof];
          acc_s[nt] = mfma16(af, bf, acc_s[nt]);
        }
      }
      float lam = sEA[63];
#pragma unroll
      for (int nt = 0; nt < 2; ++nt)
#pragma unroll
        for (int rr = 0; rr < 4; ++rr) {
          int p = lq * 16 + lg * 4 + rr;
          int n = wh * 32 + nt * 16 + lr;
          float ns = lam * sS[p][n] + acc_s[nt][rr];
          sS[p][n] = ns;
          sSb[p][n] = f2bf(ns);
        }
    }
    __syncthreads();  // bar4
  }
}

// ---------------- Deff = x @ fc_D_w^T + D  (MFMA, split-K, 32 rows/block) ----------------
__global__ __launch_bounds__(256) void k_deff(const u16* __restrict__ xcv,
                                              const u16* __restrict__ fwb,
                                              const float* __restrict__ Dv,
                                              float* __restrict__ deff) {
  __shared__ float red[2][64][8];
  const int tid = threadIdx.x, wave = tid >> 6, lane = tid & 63;
  const int lr = lane & 15, lg = lane >> 4;
  const int rowg = wave & 1;
  const int kg = wave >> 1;
  const int rb = blockIdx.x * 32 + rowg * 16;
  const u16* xrow = xcv + (size_t)(rb + lr) * DINNER + kg * 1024 + lg * 8;
  const u16* f0 = fwb + (size_t)lr * DINNER + kg * 1024 + lg * 8;
  const u16* f1 = fwb + (size_t)(16 + lr) * DINNER + kg * 1024 + lg * 8;
  f32x4 a0 = {}, a1 = {};
  for (int k = 0; k < 1024; k += 32) {
    short8 bf = *(const short8*)(xrow + k);
    short8 af0 = *(const short8*)(f0 + k);
    short8 af1 = *(const short8*)(f1 + k);
    a0 = mfma16(af0, bf, a0);
    a1 = mfma16(af1, bf, a1);
  }
  if (kg == 1) {
#pragma unroll
    for (int rr = 0; rr < 4; ++rr) {
      red[rowg][lane][rr] = a0[rr];
      red[rowg][lane][4 + rr] = a1[rr];
    }
  }
  __syncthreads();
  if (kg == 0) {
    float4 o0, o1;
#pragma unroll
    for (int rr = 0; rr < 4; ++rr) {
      ((float*)&o0)[rr] = a0[rr] + red[rowg][lane][rr] + Dv[lg * 4 + rr];
      ((float*)&o1)[rr] = a1[rr] + red[rowg][lane][4 + rr] + Dv[16 + lg * 4 + rr];
    }
    *(float4*)&deff[(size_t)(rb + lr) * NH + lg * 4] = o0;
    *(float4*)&deff[(size_t)(rb + lr) * NH + 16 + lg * 4] = o1;
  }
}

// ---------------- gating: yn = rmsnorm((y0 + y1 + x*Deff) * silu(z)) * gnw ----------------
__global__ __launch_bounds__(256) void k_gate(const u16* __restrict__ yb0,
                                              const u16* __restrict__ yb1,
                                              const u16* __restrict__ xcv,
                                              const float* __restrict__ deff,
                                              const u16* __restrict__ zb,
                                              const float* __restrict__ gnw,
                                              u16* __restrict__ yn) {
  int row = blockIdx.x, t = threadIdx.x;
  size_t base = (size_t)row * DINNER + t * 8;
  ushort8 y0v = *(const ushort8*)(yb0 + base);
  ushort8 y1v = *(const ushort8*)(yb1 + base);
  ushort8 xv = *(const ushort8*)(xcv + base);
  ushort8 zv = *(const ushort8*)(zb + base);
  float de = deff[row * NH + (t >> 3)];
  float g[8];
  float ss = 0.f;
#pragma unroll
  for (int j = 0; j < 8; ++j) {
    float y = bf2f(y0v[j]) + bf2f(y1v[j]) + bf2f(xv[j]) * de;
    float z = bf2f(zv[j]);
    float gg = y * (z / (1.f + expf(-z)));
    g[j] = gg;
    ss += gg * gg;
  }
  for (int m = 32; m; m >>= 1) ss += __shfl_xor(ss, m);
  __shared__ float wsum[4];
  if ((t & 63) == 0) wsum[t >> 6] = ss;
  __syncthreads();
  float tot = wsum[0] + wsum[1] + wsum[2] + wsum[3];
  float rinv = rsqrtf(tot * (1.0f / DINNER) + 1e-5f);
  u32 w0 = (u32)f2bf(g[0] * rinv * gnw[t * 8 + 0]) | ((u32)f2bf(g[1] * rinv * gnw[t * 8 + 1]) << 16);
  u32 w1 = (u32)f2bf(g[2] * rinv * gnw[t * 8 + 2]) | ((u32)f2bf(g[3] * rinv * gnw[t * 8 + 3]) << 16);
  u32 w2 = (u32)f2bf(g[4] * rinv * gnw[t * 8 + 4]) | ((u32)f2bf(g[5] * rinv * gnw[t * 8 + 5]) << 16);
  u32 w3 = (u32)f2bf(g[6] * rinv * gnw[t * 8 + 6]) | ((u32)f2bf(g[7] * rinv * gnw[t * 8 + 7]) << 16);
  *(uint4*)(yn + base) = make_uint4(w0, w1, w2, w3);
}

extern "C" void kernel_launch(void* const* d_in, const int* in_sizes, int n_in,
                              void* d_out, int out_size, void* d_ws, size_t ws_size,
                              hipStream_t stream) {
  (void)in_sizes; (void)n_in; (void)out_size; (void)ws_size;
  const float* hid = (const float*)d_in[0];
  const float* resin = (const float*)d_in[1];
  const float* nw = (const float*)d_in[2];
  const float* w1 = (const float*)d_in[3];
  const float* cw = (const float*)d_in[4];
  const float* cb = (const float*)d_in[5];
  const float* dtb = (const float*)d_in[6];
  const float* alog = (const float*)d_in[7];
  const float* Dv = (const float*)d_in[8];
  const float* fcw = (const float*)d_in[9];
  const float* gnw = (const float*)d_in[10];
  const float* w2 = (const float*)d_in[11];
  float* out = (float*)d_out;
  float* resout = out + (size_t)ROWS * DMODEL;

  char* ws = (char*)d_ws;
  size_t o = 0;
  auto alloc = [&](size_t bytes) {
    char* p = ws + o;
    o += (bytes + 255) & ~(size_t)255;
    return p;
  };
  u16* W1b = (u16*)alloc((size_t)DIP_PAD * DMODEL * 2);  // 8.9 MB (reused for W2b)
  u16* HN = (u16*)alloc((size_t)ROWS * DMODEL * 2);      // 16.8 MB (reused for YN)
  u16* XBC = (u16*)alloc((size_t)ROWS * CONVD * 2);      // 35.7 MB (reused for YB0)
  u16* ZB = (u16*)alloc((size_t)ROWS * DINNER * 2);      // 33.6 MB
  u16* XC = (u16*)alloc((size_t)ROWS * DINNER * 2);      // 33.6 MB
  u16* BM = (u16*)alloc((size_t)ROWS * 64 * 2);          // 1 MB
  u16* CM = (u16*)alloc((size_t)ROWS * 64 * 2);          // 1 MB
  float* DT = (float*)alloc((size_t)8 * LSEQ * NH * 4);  // 2 MB
  float* DE = (float*)alloc((size_t)ROWS * NH * 4);      // 1 MB
  u16* FWB = (u16*)alloc((size_t)NH * DINNER * 2);       // 128 KB
  u16* YB0 = XBC;
  u16* YB1 = (u16*)out;  // out region (33.55 MB) is dead until final GEMM
  u16* W2b = W1b;
  u16* YN = HN;

  k_cast<<<(DIP * DMODEL) / 1024, 256, 0, stream>>>(w1, W1b);
  k_addnorm<<<ROWS, 256, 0, stream>>>(hid, resin, nw, resout, HN);
  // in_proj: M=8192 (64 tiles of 128), N=4352 (17 tiles of 256), K=1024
  k_gemm<0><<<64 * 17, 512, 0, stream>>>(HN, W1b, DMODEL, 17, nullptr, ZB, XBC, DT, dtb);
  k_conv<<<(ROWS / 4) * 272 / 256, 256, 0, stream>>>(XBC, cw, cb, XC, BM, CM);
  k_ssd<<<256, 512, 0, stream>>>(XC, BM, CM, DT, alog, YB0, YB1);
  k_cast<<<(DMODEL * DINNER) / 1024, 256, 0, stream>>>(w2, W2b);
  k_cast<<<(NH * DINNER) / 1024, 256, 0, stream>>>(fcw, FWB);
  k_deff<<<ROWS / 32, 256, 0, stream>>>(XC, FWB, Dv, DE);
  k_gate<<<ROWS, 256, 0, stream>>>(YB0, YB1, XC, DE, ZB, gnw, YN);
  // out_proj: M=8192 (64 tiles), N=1024 (4 tiles of 256), K=2048
  k_gemm<1><<<64 * 4, 512, 0, stream>>>(YN, W2b, DINNER, 4, out, nullptr, nullptr, nullptr,
                                        nullptr);
}

// Round 13
// 400.969 us; speedup vs baseline: 1.2636x; 1.0152x over previous
//
#include <hip/hip_runtime.h>

typedef __attribute__((ext_vector_type(4))) float f32x4;
typedef __attribute__((ext_vector_type(8))) short short8;
typedef __attribute__((ext_vector_type(8))) unsigned short ushort8;
typedef unsigned short u16;
typedef unsigned int u32;

#define DMODEL 1024
#define DINNER 2048
#define NH     32
#define DIP    4288
#define DIP_PAD 4352
#define CONVD  2176
#define LSEQ   2048
#define ROWS   8192
#define NCHUNK 32

static __device__ __forceinline__ float bf2f(u16 u) {
  u32 x = ((u32)u) << 16;
  return __builtin_bit_cast(float, x);
}
static __device__ __forceinline__ u16 f2bf(float f) {
  u32 x = __builtin_bit_cast(u32, f);
  x += 0x7fffu + ((x >> 16) & 1u);
  return (u16)(x >> 16);
}
static __device__ __forceinline__ f32x4 mfma16(short8 a, short8 b, f32x4 c) {
  return __builtin_amdgcn_mfma_f32_16x16x32_bf16(a, b, c, 0, 0, 0);
}

#define GLDS(gp, lp)                                                     \
  __builtin_amdgcn_global_load_lds(                                     \
      (const __attribute__((address_space(1))) void*)(gp),              \
      (__attribute__((address_space(3))) void*)(lp), 16, 0, 0)

// ---------------- f32 -> bf16 weight cast ----------------
__global__ __launch_bounds__(256) void k_cast(const float* __restrict__ s, u16* __restrict__ d) {
  size_t i = ((size_t)blockIdx.x * 256 + threadIdx.x) * 4;
  float4 v = *(const float4*)(s + i);
  u32 lo = (u32)f2bf(v.x) | ((u32)f2bf(v.y) << 16);
  u32 hi = (u32)f2bf(v.z) | ((u32)f2bf(v.w) << 16);
  *(uint2*)(d + i) = make_uint2(lo, hi);
}

// ---------------- res = h + r ; hnorm = rmsnorm(res)*w (bf16) ----------------
__global__ __launch_bounds__(256) void k_addnorm(const float* __restrict__ h,
                                                 const float* __restrict__ r,
                                                 const float* __restrict__ nw,
                                                 float* __restrict__ res,
                                                 u16* __restrict__ hn) {
  int row = blockIdx.x, t = threadIdx.x;
  const float4* hp = (const float4*)(h + (size_t)row * DMODEL);
  const float4* rp = (const float4*)(r + (size_t)row * DMODEL);
  float4 a = hp[t], b = rp[t];
  float4 s;
  s.x = a.x + b.x; s.y = a.y + b.y; s.z = a.z + b.z; s.w = a.w + b.w;
  ((float4*)(res + (size_t)row * DMODEL))[t] = s;
  float ss = s.x * s.x + s.y * s.y + s.z * s.z + s.w * s.w;
  for (int m = 32; m; m >>= 1) ss += __shfl_xor(ss, m);
  __shared__ float wsum[4];
  if ((t & 63) == 0) wsum[t >> 6] = ss;
  __syncthreads();
  float tot = wsum[0] + wsum[1] + wsum[2] + wsum[3];
  float rinv = rsqrtf(tot * (1.0f / DMODEL) + 1e-5f);
  float4 w4 = ((const float4*)nw)[t];
  u32 lo = (u32)f2bf(s.x * rinv * w4.x) | ((u32)f2bf(s.y * rinv * w4.y) << 16);
  u32 hi = (u32)f2bf(s.z * rinv * w4.z) | ((u32)f2bf(s.w * rinv * w4.w) << 16);
  *(uint2*)(hn + (size_t)row * DMODEL + t * 4) = make_uint2(lo, hi);
}

// ---------------- bf16 MFMA GEMM: 128x128 tile, 4 waves, BK=64 ----------------
// Round-8 single-barrier 2-phase loop, tile halved for 2 blocks/CU (this round's
// ONE change): LDS 2 x 32 KB = 64 KB -> two independent barrier domains per CU;
// while one block drains vmcnt(0)+barrier, the other's waves compute.
// A-panel-linear XCD remap (proven best of three tested).
template <int MODE>
__global__ __launch_bounds__(256) void k_gemm(const u16* __restrict__ A,
                                              const u16* __restrict__ Bw, int K, int nN,
                                              float* __restrict__ outf,
                                              u16* __restrict__ zb, u16* __restrict__ xb,
                                              float* __restrict__ dtp,
                                              const float* __restrict__ dt_bias) {
  constexpr int ABY = 128 * 64 * 2;   // 16 KB A tile
  constexpr int TB = 2 * ABY;         // 32 KB per buffer (A+B)
  __shared__ char lds[2 * TB];        // 64 KB

  const int tid = threadIdx.x, wave = tid >> 6, lane = tid & 63;
  const int wm = wave >> 1, wn = wave & 1;
  const int lr = lane & 15, lg = lane >> 4;

  const int cpx = gridDim.x >> 3;
  const int orig = blockIdx.x;
  const int wg = (orig & 7) * cpx + (orig >> 3);
  const int brow = (wg / nN) * 128;
  const int bcol = (wg % nN) * 128;
  const int NK = K >> 6;

  size_t srcA[4], srcB[4];
#pragma unroll
  for (int g = 0; g < 4; ++g) {
    int d = g * 4096 + tid * 16;
    int s = d ^ (((d >> 7) & 7) << 4);
    srcA[g] = (size_t)(brow + (s >> 7)) * K + ((s & 127) >> 1);
    srcB[g] = (size_t)(bcol + (s >> 7)) * K + ((s & 127) >> 1);
  }

  auto STAGE = [&](int buf, int kt) {
    char* base = lds + buf * TB;
    size_t koff = (size_t)kt * 64;
#pragma unroll
    for (int g = 0; g < 4; ++g)
      GLDS(A + srcA[g] + koff, base + g * 4096 + wave * 1024);
#pragma unroll
    for (int g = 0; g < 4; ++g)
      GLDS(Bw + srcB[g] + koff, base + ABY + g * 4096 + wave * 1024);
  };

  int offA[4][2], offB[4][2];
#pragma unroll
  for (int i = 0; i < 4; ++i)
#pragma unroll
    for (int ks = 0; ks < 2; ++ks) {
      int rA = wm * 64 + i * 16 + lr;
      offA[i][ks] = (rA * 128 + ks * 64 + lg * 16) ^ ((lr & 7) << 4);
      int rB = wn * 64 + i * 16 + lr;
      offB[i][ks] = ABY + ((rB * 128 + ks * 64 + lg * 16) ^ ((lr & 7) << 4));
    }

  f32x4 acc[4][4] = {};
  STAGE(0, 0);
  asm volatile("s_waitcnt vmcnt(0)" ::: "memory");
  __builtin_amdgcn_s_barrier();
  for (int t = 0; t < NK; ++t) {
    const int cur = t & 1;
    if (t + 1 < NK) STAGE(cur ^ 1, t + 1);
    const char* bb = lds + cur * TB;
    short8 af[4], bfr[4];
#pragma unroll
    for (int i = 0; i < 4; ++i) af[i] = *(const short8*)(bb + offA[i][0]);
#pragma unroll
    for (int j = 0; j < 4; ++j) bfr[j] = *(const short8*)(bb + offB[j][0]);
    __builtin_amdgcn_s_setprio(1);
#pragma unroll
    for (int i = 0; i < 4; ++i)
#pragma unroll
      for (int j = 0; j < 4; ++j) acc[i][j] = mfma16(af[i], bfr[j], acc[i][j]);
    __builtin_amdgcn_s_setprio(0);
#pragma unroll
    for (int i = 0; i < 4; ++i) af[i] = *(const short8*)(bb + offA[i][1]);
#pragma unroll
    for (int j = 0; j < 4; ++j) bfr[j] = *(const short8*)(bb + offB[j][1]);
    __builtin_amdgcn_s_setprio(1);
#pragma unroll
    for (int i = 0; i < 4; ++i)
#pragma unroll
      for (int j = 0; j < 4; ++j) acc[i][j] = mfma16(af[i], bfr[j], acc[i][j]);
    __builtin_amdgcn_s_setprio(0);
    if (t + 1 < NK) {
      asm volatile("s_waitcnt vmcnt(0)" ::: "memory");
      __builtin_amdgcn_s_barrier();
    }
  }

  const int mb = brow + wm * 64 + lg * 4;
  const int nb = bcol + wn * 64 + lr;
#pragma unroll
  for (int i = 0; i < 4; ++i)
#pragma unroll
    for (int j = 0; j < 4; ++j)
#pragma unroll
      for (int rr = 0; rr < 4; ++rr) {
        int m = mb + i * 16 + rr;
        int n = nb + j * 16;
        float v = acc[i][j][rr];
        if constexpr (MODE == 1) {
          outf[(size_t)m * 1024 + n] = v;
        } else {
          if (n < DINNER) {
            zb[(size_t)m * DINNER + n] = f2bf(v);
          } else if (n < DINNER + CONVD) {
            xb[(size_t)m * CONVD + (n - DINNER)] = f2bf(v);
          } else if (n < DIP) {
            int h2 = n - (DINNER + CONVD);  // 0..63
            float uu = v + dt_bias[h2 & 31];
            float sp = (uu > 20.f) ? uu : log1pf(expf(uu));
            int bb2 = m >> 11, tt = m & 2047;
            int obb = bb2, ot = tt;
            if (h2 >= 32) { obb = bb2 + 4; ot = 2047 - tt; }
            dtp[((size_t)(obb << 11) + ot) * NH + (h2 & 31)] = sp;
          }
        }
      }
}

// ---------------- depthwise causal conv (k=4) + SiLU, 8 chans x 4 t-steps/thread ----------------
__global__ __launch_bounds__(256) void k_conv(const u16* __restrict__ xbc,
                                              const float* __restrict__ cw,
                                              const float* __restrict__ cb,
                                              u16* __restrict__ xc, u16* __restrict__ bm,
                                              u16* __restrict__ cm) {
  int e = blockIdx.x * 256 + threadIdx.x;  // e < (ROWS/4)*272 = 557056
  int c8 = e % 272;
  int rq = e / 272;          // (b, t-group)
  int b = rq >> 9;           // rq / 512
  int t0 = (rq & 511) * 4;   // first of 4 t values
  int c = c8 * 8;

  float4 w[8];
  float a[4][8];
#pragma unroll
  for (int j = 0; j < 8; ++j) {
    w[j] = *(const float4*)&cw[(c + j) * 4];
    float bias = cb[c + j];
#pragma unroll
    for (int i = 0; i < 4; ++i) a[i][j] = bias;
  }
  const u16* base = xbc + (size_t)(b << 11) * CONVD + c;
#pragma unroll
  for (int k = 0; k < 7; ++k) {
    int tt = t0 - 3 + k;
    if (tt >= 0) {
      ushort8 v = *(const ushort8*)(base + (size_t)tt * CONVD);
#pragma unroll
      for (int i = 0; i < 4; ++i) {
        int kk = k - i;  // tap index for output i
        if (kk >= 0 && kk < 4) {
#pragma unroll
          for (int j = 0; j < 8; ++j) a[i][j] += bf2f(v[j]) * ((const float*)&w[j])[kk];
        }
      }
    }
  }
#pragma unroll
  for (int i = 0; i < 4; ++i) {
    ushort8 o;
#pragma unroll
    for (int j = 0; j < 8; ++j) {
      float s = a[i][j] * (1.f / (1.f + expf(-a[i][j])));
      o[j] = f2bf(s);
    }
    size_t r = (size_t)(b << 11) + t0 + i;
    if (c8 < 256) *(ushort8*)(xc + r * DINNER + c) = o;
    else if (c8 < 264) *(ushort8*)(bm + r * 64 + (c - DINNER)) = o;
    else *(ushort8*)(cm + r * 64 + (c - DINNER - 64)) = o;
  }
}

// ---------------- fused SSD scan v2: 8 waves, one block per (dir, batch, head) ----------------
__global__ __launch_bounds__(512) void k_ssd(const u16* __restrict__ xc,
                                             const u16* __restrict__ bmat,
                                             const u16* __restrict__ cmat,
                                             const float* __restrict__ dtp,
                                             const float* __restrict__ alog,
                                             u16* __restrict__ y0, u16* __restrict__ y1) {
  const int h = blockIdx.x & 31;
  const int grp = blockIdx.x >> 5;  // 0..7
  const int dir = grp >> 2;
  const int bt = grp & 3;
  const int tid = threadIdx.x, wave = tid >> 6, lane = tid & 63;
  const int lq = wave >> 1, wh = wave & 1;
  const int lr = lane & 15, lg = lane >> 4;
  const float Ah = -expf(alog[h]);

  __shared__ u16 sB[64][72];    // [s][n]
  __shared__ u16 sC[64][72];    // [s][n]
  __shared__ u16 sXM[64][72];   // staged X [s][p]; reused as M [l][s] after transpose
  __shared__ u16 sXT[64][72];   // X^T [p][s]
  __shared__ u16 sBT[64][72];   // B^T [n][s]
  __shared__ u16 sSb[64][72];   // bf16 shadow of state [p][n]
  __shared__ float sS[64][68];  // f32 state accumulator [p][n]
  __shared__ float sAc[64], sEA[64], sSc[64], sDt[64];

  for (int i = tid; i < 64 * 64; i += 512) {
    sS[i >> 6][i & 63] = 0.f;
    sSb[i >> 6][i & 63] = 0;
  }

  const int srow = tid >> 3, q8 = (tid & 7) * 8;

  auto rowOf = [&](int c) {
    int tdir = c * 64 + srow;
    return bt * LSEQ + (dir ? (LSEQ - 1 - tdir) : tdir);
  };

  int rg = rowOf(0);
  ushort8 rB = *(const ushort8*)(bmat + (size_t)rg * 64 + q8);
  ushort8 rC = *(const ushort8*)(cmat + (size_t)rg * 64 + q8);
  ushort8 rX = *(const ushort8*)(xc + (size_t)rg * DINNER + h * 64 + q8);

  for (int c = 0; c < NCHUNK; ++c) {
    // ---- stage (regs -> LDS) ----
    *(ushort8*)&sB[srow][q8] = rB;
    *(ushort8*)&sC[srow][q8] = rC;
    *(ushort8*)&sXM[srow][q8] = rX;
    __syncthreads();  // bar1

    // ---- transpose X, B (wave reads rows w*8..w*8+7, lane = column) + dt scan ----
    {
      ushort8 vx, vb;
#pragma unroll
      for (int i = 0; i < 8; ++i) {
        vx[i] = sXM[wave * 8 + i][lane];
        vb[i] = sB[wave * 8 + i][lane];
      }
      *(ushort8*)&sXT[lane][wave * 8] = vx;
      *(ushort8*)&sBT[lane][wave * 8] = vb;
    }
    if (wave == 0) {
      int s = lane;
      float dv = dtp[((size_t)grp * LSEQ + c * 64 + s) * NH + h];
      float a = dv * Ah;
      float x = a;
#pragma unroll
      for (int d = 1; d < 64; d <<= 1) {
        float y = __shfl_up(x, d);
        if (s >= d) x += y;
      }
      float tot = __shfl(x, 63);
      sAc[s] = x;
      sEA[s] = expf(x);
      sSc[s] = expf(tot - x) * dv;
      sDt[s] = dv;
    }
    __syncthreads();  // bar2

    // ---- early-issue next chunk's global loads (land during PA/PB) ----
    if (c + 1 < NCHUNK) {
      int rg2 = rowOf(c + 1);
      rB = *(const ushort8*)(bmat + (size_t)rg2 * 64 + q8);
      rC = *(const ushort8*)(cmat + (size_t)rg2 * 64 + q8);
      rX = *(const ushort8*)(xc + (size_t)rg2 * DINNER + h * 64 + q8);
    }

    // ---- PA: G = C@B^T -> M (into sXM); Yoff = C @ sSb^T ----
    f32x4 acc_y[2] = {};
    {
      f32x4 acc_g[2] = {};
#pragma unroll
      for (int ks = 0; ks < 2; ++ks) {
        int kof = ks * 32 + lg * 8;
        short8 af = *(const short8*)&sC[lq * 16 + lr][kof];
#pragma unroll
        for (int nt = 0; nt < 2; ++nt) {
          short8 bf = *(const short8*)&sB[wh * 32 + nt * 16 + lr][kof];
          acc_g[nt] = mfma16(af, bf, acc_g[nt]);
        }
      }
#pragma unroll
      for (int ks = 0; ks < 2; ++ks) {
        int kof = ks * 32 + lg * 8;
        short8 af = *(const short8*)&sC[lq * 16 + lr][kof];
#pragma unroll
        for (int nt = 0; nt < 2; ++nt) {
          short8 bf = *(const short8*)&sSb[wh * 32 + nt * 16 + lr][kof];
          acc_y[nt] = mfma16(af, bf, acc_y[nt]);
        }
      }
#pragma unroll
      for (int nt = 0; nt < 2; ++nt)
#pragma unroll
        for (int rr = 0; rr < 4; ++rr) {
          int l = lq * 16 + lg * 4 + rr;
          int s = wh * 32 + nt * 16 + lr;
          float g = acc_g[nt][rr];
          float m = (l >= s) ? g * sDt[s] * expf(sAc[l] - sAc[s]) : 0.f;
          sXM[l][s] = f2bf(m);
        }
    }
    __syncthreads();  // bar3

    // ---- PB: Y = Yoff*exp(Ac) + M@X^T; store; S update ----
#pragma unroll
    for (int nt = 0; nt < 2; ++nt)
#pragma unroll
      for (int rr = 0; rr < 4; ++rr) acc_y[nt][rr] *= sEA[lq * 16 + lg * 4 + rr];
#pragma unroll
    for (int ks = 0; ks < 2; ++ks) {
      int kof = ks * 32 + lg * 8;
      short8 af = *(const short8*)&sXM[lq * 16 + lr][kof];
#pragma unroll
      for (int nt = 0; nt < 2; ++nt) {
        short8 bf = *(const short8*)&sXT[wh * 32 + nt * 16 + lr][kof];
        acc_y[nt] = mfma16(af, bf, acc_y[nt]);
      }
    }
#pragma unroll
    for (int nt = 0; nt < 2; ++nt)
#pragma unroll
      for (int rr = 0; rr < 4; ++rr) {
        int l = lq * 16 + lg * 4 + rr;
        int p = wh * 32 + nt * 16 + lr;
        int tg = c * 64 + l;
        if (tg <= LSEQ - 2) {
          float v = acc_y[nt][rr];
          if (dir == 0)
            y0[((size_t)bt * LSEQ + tg + 1) * DINNER + h * 64 + p] = f2bf(v);
          else
            y1[((size_t)bt * LSEQ + (LSEQ - 2 - tg)) * DINNER + h * 64 + p] = f2bf(v);
        }
      }
    if (c == 0 && tid < 64) {
      if (dir == 0)
        y0[((size_t)bt * LSEQ) * DINNER + h * 64 + tid] = 0;
      else
        y1[((size_t)bt * LSEQ + (LSEQ - 1)) * DINNER + h * 64 + tid] = 0;
    }
    // chunk state: S = lam*S + (X*w)^T @ B
    {
      f32x4 acc_s[2] = {};
#pragma unroll
      for (int ks = 0; ks < 2; ++ks) {
        int kof = ks * 32 + lg * 8;
        ushort8 xr = *(const ushort8*)&sXT[lq * 16 + lr][kof];
        short8 af;
#pragma unroll
        for (int e = 0; e < 8; ++e) af[e] = (short)f2bf(bf2f(xr[e]) * sSc[kof + e]);
#pragma unroll
        for (int nt = 0; nt < 2; ++nt) {
          short8 bf = *(const short8*)&sBT[wh * 32 + nt * 16 + lr][kof];
          acc_s[nt] = mfma16(af, bf, acc_s[nt]);
        }
      }
      float lam = sEA[63];
#pragma unroll
      for (int nt = 0; nt < 2; ++nt)
#pragma unroll
        for (int rr = 0; rr < 4; ++rr) {
          int p = lq * 16 + lg * 4 + rr;
          int n = wh * 32 + nt * 16 + lr;
          float ns = lam * sS[p][n] + acc_s[nt][rr];
          sS[p][n] = ns;
          sSb[p][n] = f2bf(ns);
        }
    }
    __syncthreads();  // bar4
  }
}

// ---------------- Deff = x @ fc_D_w^T + D  (MFMA, split-K, 32 rows/block) ----------------
__global__ __launch_bounds__(256) void k_deff(const u16* __restrict__ xcv,
                                              const u16* __restrict__ fwb,
                                              const float* __restrict__ Dv,
                                              float* __restrict__ deff) {
  __shared__ float red[2][64][8];
  const int tid = threadIdx.x, wave = tid >> 6, lane = tid & 63;
  const int lr = lane & 15, lg = lane >> 4;
  const int rowg = wave & 1;
  const int kg = wave >> 1;
  const int rb = blockIdx.x * 32 + rowg * 16;
  const u16* xrow = xcv + (size_t)(rb + lr) * DINNER + kg * 1024 + lg * 8;
  const u16* f0 = fwb + (size_t)lr * DINNER + kg * 1024 + lg * 8;
  const u16* f1 = fwb + (size_t)(16 + lr) * DINNER + kg * 1024 + lg * 8;
  f32x4 a0 = {}, a1 = {};
  for (int k = 0; k < 1024; k += 32) {
    short8 bf = *(const short8*)(xrow + k);
    short8 af0 = *(const short8*)(f0 + k);
    short8 af1 = *(const short8*)(f1 + k);
    a0 = mfma16(af0, bf, a0);
    a1 = mfma16(af1, bf, a1);
  }
  if (kg == 1) {
#pragma unroll
    for (int rr = 0; rr < 4; ++rr) {
      red[rowg][lane][rr] = a0[rr];
      red[rowg][lane][4 + rr] = a1[rr];
    }
  }
  __syncthreads();
  if (kg == 0) {
    float4 o0, o1;
#pragma unroll
    for (int rr = 0; rr < 4; ++rr) {
      ((float*)&o0)[rr] = a0[rr] + red[rowg][lane][rr] + Dv[lg * 4 + rr];
      ((float*)&o1)[rr] = a1[rr] + red[rowg][lane][4 + rr] + Dv[16 + lg * 4 + rr];
    }
    *(float4*)&deff[(size_t)(rb + lr) * NH + lg * 4] = o0;
    *(float4*)&deff[(size_t)(rb + lr) * NH + 16 + lg * 4] = o1;
  }
}

// ---------------- gating: yn = rmsnorm((y0 + y1 + x*Deff) * silu(z)) * gnw ----------------
__global__ __launch_bounds__(256) void k_gate(const u16* __restrict__ yb0,
                                              const u16* __restrict__ yb1,
                                              const u16* __restrict__ xcv,
                                              const float* __restrict__ deff,
                                              const u16* __restrict__ zb,
                                              const float* __restrict__ gnw,
                                              u16* __restrict__ yn) {
  int row = blockIdx.x, t = threadIdx.x;
  size_t base = (size_t)row * DINNER + t * 8;
  ushort8 y0v = *(const ushort8*)(yb0 + base);
  ushort8 y1v = *(const ushort8*)(yb1 + base);
  ushort8 xv = *(const ushort8*)(xcv + base);
  ushort8 zv = *(const ushort8*)(zb + base);
  float de = deff[row * NH + (t >> 3)];
  float g[8];
  float ss = 0.f;
#pragma unroll
  for (int j = 0; j < 8; ++j) {
    float y = bf2f(y0v[j]) + bf2f(y1v[j]) + bf2f(xv[j]) * de;
    float z = bf2f(zv[j]);
    float gg = y * (z / (1.f + expf(-z)));
    g[j] = gg;
    ss += gg * gg;
  }
  for (int m = 32; m; m >>= 1) ss += __shfl_xor(ss, m);
  __shared__ float wsum[4];
  if ((t & 63) == 0) wsum[t >> 6] = ss;
  __syncthreads();
  float tot = wsum[0] + wsum[1] + wsum[2] + wsum[3];
  float rinv = rsqrtf(tot * (1.0f / DINNER) + 1e-5f);
  u32 w0 = (u32)f2bf(g[0] * rinv * gnw[t * 8 + 0]) | ((u32)f2bf(g[1] * rinv * gnw[t * 8 + 1]) << 16);
  u32 w1 = (u32)f2bf(g[2] * rinv * gnw[t * 8 + 2]) | ((u32)f2bf(g[3] * rinv * gnw[t * 8 + 3]) << 16);
  u32 w2 = (u32)f2bf(g[4] * rinv * gnw[t * 8 + 4]) | ((u32)f2bf(g[5] * rinv * gnw[t * 8 + 5]) << 16);
  u32 w3 = (u32)f2bf(g[6] * rinv * gnw[t * 8 + 6]) | ((u32)f2bf(g[7] * rinv * gnw[t * 8 + 7]) << 16);
  *(uint4*)(yn + base) = make_uint4(w0, w1, w2, w3);
}

extern "C" void kernel_launch(void* const* d_in, const int* in_sizes, int n_in,
                              void* d_out, int out_size, void* d_ws, size_t ws_size,
                              hipStream_t stream) {
  (void)in_sizes; (void)n_in; (void)out_size; (void)ws_size;
  const float* hid = (const float*)d_in[0];
  const float* resin = (const float*)d_in[1];
  const float* nw = (const float*)d_in[2];
  const float* w1 = (const float*)d_in[3];
  const float* cw = (const float*)d_in[4];
  const float* cb = (const float*)d_in[5];
  const float* dtb = (const float*)d_in[6];
  const float* alog = (const float*)d_in[7];
  const float* Dv = (const float*)d_in[8];
  const float* fcw = (const float*)d_in[9];
  const float* gnw = (const float*)d_in[10];
  const float* w2 = (const float*)d_in[11];
  float* out = (float*)d_out;
  float* resout = out + (size_t)ROWS * DMODEL;

  char* ws = (char*)d_ws;
  size_t o = 0;
  auto alloc = [&](size_t bytes) {
    char* p = ws + o;
    o += (bytes + 255) & ~(size_t)255;
    return p;
  };
  u16* W1b = (u16*)alloc((size_t)DIP_PAD * DMODEL * 2);  // 8.9 MB (reused for W2b)
  u16* HN = (u16*)alloc((size_t)ROWS * DMODEL * 2);      // 16.8 MB (reused for YN)
  u16* XBC = (u16*)alloc((size_t)ROWS * CONVD * 2);      // 35.7 MB (reused for YB0)
  u16* ZB = (u16*)alloc((size_t)ROWS * DINNER * 2);      // 33.6 MB
  u16* XC = (u16*)alloc((size_t)ROWS * DINNER * 2);      // 33.6 MB
  u16* BM = (u16*)alloc((size_t)ROWS * 64 * 2);          // 1 MB
  u16* CM = (u16*)alloc((size_t)ROWS * 64 * 2);          // 1 MB
  float* DT = (float*)alloc((size_t)8 * LSEQ * NH * 4);  // 2 MB
  float* DE = (float*)alloc((size_t)ROWS * NH * 4);      // 1 MB
  u16* FWB = (u16*)alloc((size_t)NH * DINNER * 2);       // 128 KB
  u16* YB0 = XBC;
  u16* YB1 = (u16*)out;  // out region (33.55 MB) is dead until final GEMM
  u16* W2b = W1b;
  u16* YN = HN;

  k_cast<<<(DIP * DMODEL) / 1024, 256, 0, stream>>>(w1, W1b);
  k_addnorm<<<ROWS, 256, 0, stream>>>(hid, resin, nw, resout, HN);
  // in_proj: M=8192 (64 tiles of 128), N=4352 (34 tiles of 128), K=1024
  k_gemm<0><<<64 * 34, 256, 0, stream>>>(HN, W1b, DMODEL, 34, nullptr, ZB, XBC, DT, dtb);
  k_conv<<<(ROWS / 4) * 272 / 256, 256, 0, stream>>>(XBC, cw, cb, XC, BM, CM);
  k_ssd<<<256, 512, 0, stream>>>(XC, BM, CM, DT, alog, YB0, YB1);
  k_cast<<<(DMODEL * DINNER) / 1024, 256, 0, stream>>>(w2, W2b);
  k_cast<<<(NH * DINNER) / 1024, 256, 0, stream>>>(fcw, FWB);
  k_deff<<<ROWS / 32, 256, 0, stream>>>(XC, FWB, Dv, DE);
  k_gate<<<ROWS, 256, 0, stream>>>(YB0, YB1, XC, DE, ZB, gnw, YN);
  // out_proj: M=8192 (64 tiles), N=1024 (8 tiles of 128), K=2048
  k_gemm<1><<<64 * 8, 256, 0, stream>>>(YN, W2b, DINNER, 8, out, nullptr, nullptr, nullptr,
                                        nullptr);
}